// Round 9
// baseline (415.309 us; speedup 1.0000x reference)
//
#include <hip/hip_runtime.h>
#include <hip/hip_bf16.h>
#include <stdint.h>

// ======================================================================
// EMSA fused pipeline. Device dtype (bf16 vs f32) detected at runtime.
// Algebra:
//  * S_i = Q_i K_i^T /8 once per input head (9.7 GF); head-mix tw fused
//    into the S-GEMM epilogue (two-pass, in-register); PV batched GEMM.
//  * softmax row-sums are 1  =>  instance-norm mean = 1/256 exactly
//  * Dev = P - 1/256; var = mean(Dev^2); out = (Dev@V)*rsqrt(va+eps)
//  * tb cancels in softmax; 1/sqrt(dk) folded into WqT/bq;
//    instance-norm scale folded into per-batch pre-scaled Wo^T.
// R9: gemm_s_mix v2 — NAMED accumulators (A00..A71) + macro-expanded
//     head loop. R8's array acc in a non-unrolled loop was runtime-
//     indexed -> scratch (VGPR=80 proved it) -> 194us. Nothing
//     runtime-indexable remains.
// ======================================================================

typedef __bf16 bf16;
typedef __bf16 bf16x4 __attribute__((ext_vector_type(4)));
typedef __bf16 bf16x8 __attribute__((ext_vector_type(8)));
typedef float  f32x4  __attribute__((ext_vector_type(4)));

#define LDS_AS  __attribute__((address_space(3)))
#define GLOB_AS __attribute__((address_space(1)))

__device__ __forceinline__ void gload_lds16(const bf16* g, void* l) {
    __builtin_amdgcn_global_load_lds((const GLOB_AS void*)g, (LDS_AS void*)l, 16, 0, 0);
}

// ---------------- constants ----------------
#define NB   16
#define NQ   2304
#define DD   512
#define NKV  256

// workspace layout (bytes)
constexpr size_t OFF_WQT = 0;
constexpr size_t OFF_WKT = 512*512*2;
constexpr size_t OFF_WVT = 2*512*512*2;
constexpr size_t OFF_WOT = 3*512*512*2;
constexpr size_t OFF_X   = 4*512*512*2;
constexpr size_t OFF_KT  = OFF_X  + 4194304;
constexpr size_t OFF_VT  = OFF_KT + 4194304;
constexpr size_t OFF_SS  = OFF_VT + 4194304;
constexpr size_t OFF_SM  = OFF_SS + 512;
constexpr size_t OFF_TWF = OFF_SM + 24064;
constexpr size_t OFF_FLG = OFF_TWF + 256;
constexpr size_t OFF_QF  = OFF_FLG + 256;
constexpr size_t OFF_U   = OFF_QF + (size_t)NB*NQ*DD*2;
constexpr size_t OFF_S   = OFF_U  + (size_t)NB*NQ*DD*2;   // Dev chunk buffer
constexpr size_t SPLANE  = (size_t)NQ*NKV*2;
constexpr size_t OFF_WOTP = OFF_X;   // aliases X+KT (dead by scale_wot)

// small-region element offsets
#define SM_BQ  0
#define SM_BK  512
#define SM_BV  1024
#define SM_BO  1536
#define SM_SRW 2048
#define SM_SRB 10240
#define SM_LNG 10752
#define SM_LNB 11264
#define SM_TW  11776

// ---------------- dtype detection ----------------
__global__ __launch_bounds__(64) void detect_dtype(const uint32_t* __restrict__ q,
                                                   int* __restrict__ flag)
{
    int t = threadIdx.x;
    int cnt = 0;
    #pragma unroll
    for (int i = 0; i < 8; i++) {
        uint32_t w = q[t*8 + i];
        int e = (w >> 7) & 0xFF;
        cnt += (e >= 100 && e <= 150) ? 1 : 0;
    }
    #pragma unroll
    for (int m = 1; m < 64; m <<= 1) cnt += __shfl_xor(cnt, m);
    if (t == 0) *flag = (cnt >= 384) ? 0 : 1;   // 0=bf16, 1=f32
}

// ---------------- input conversion (work only for f32 input) ----------------
__global__ __launch_bounds__(256) void convert_q(const void* __restrict__ in,
                                                 bf16* __restrict__ out,
                                                 const int* __restrict__ flag)
{
    if (*flag == 0) return;
    int idx = blockIdx.x * 256 + threadIdx.x;
    f32x4 a = ((const f32x4*)in)[(size_t)idx*2];
    f32x4 b = ((const f32x4*)in)[(size_t)idx*2 + 1];
    bf16x8 r;
    #pragma unroll
    for (int i = 0; i < 4; i++) { r[i] = (bf16)a[i]; r[i+4] = (bf16)b[i]; }
    ((bf16x8*)out)[idx] = r;
}

__global__ __launch_bounds__(256) void convert_small(
    const void* s0, const void* s1, const void* s2, const void* s3,
    const void* s4, const void* s5, const void* s6, const void* s7,
    const void* s8, bf16* __restrict__ dst, float* __restrict__ twf,
    const int* __restrict__ flag)
{
    const void* srcs[9] = {s0,s1,s2,s3,s4,s5,s6,s7,s8};
    const int sizes[9]  = {512,512,512,512,8192,512,512,512,64};
    const int offs[9]   = {SM_BQ,SM_BK,SM_BV,SM_BO,SM_SRW,SM_SRB,SM_LNG,SM_LNB,SM_TW};
    const float scl[9]  = {0.125f,1.f,1.f,1.f,1.f,1.f,1.f,1.f,1.f};
    int b = blockIdx.x;
    const void* s = srcs[b];
    int n = sizes[b], o = offs[b];
    float sc = scl[b];
    bool f32 = (*flag != 0);
    for (int i = threadIdx.x; i < n; i += 256) {
        float v = f32 ? ((const float*)s)[i] : (float)((const bf16*)s)[i];
        dst[o + i] = (bf16)(v * sc);
        if (b == 8) twf[i] = v;
    }
}

// ---------------- weight transpose (512x512) ----------------
__global__ __launch_bounds__(256) void transpose512(
    const void* s0, const void* s1, const void* s2, const void* s3,
    bf16* __restrict__ d0, bf16* __restrict__ d1,
    bf16* __restrict__ d2, bf16* __restrict__ d3,
    const int* __restrict__ flag)
{
    __shared__ bf16 tile[32][33];
    bool f32 = (*flag != 0);
    int wsel = blockIdx.z;
    const void* src = wsel == 0 ? s0 : wsel == 1 ? s1 : wsel == 2 ? s2 : s3;
    bf16*       dst = wsel == 0 ? d0 : wsel == 1 ? d1 : wsel == 2 ? d2 : d3;
    float scl = (wsel == 0) ? 0.125f : 1.0f;
    int c0 = blockIdx.x * 32, n0 = blockIdx.y * 32;
    int tx = threadIdx.x, ty = threadIdx.y;
    #pragma unroll
    for (int i = 0; i < 4; i++) {
        size_t idx = (size_t)(c0 + ty + i*8) * 512 + n0 + tx;
        float v = f32 ? ((const float*)src)[idx] : (float)((const bf16*)src)[idx];
        tile[ty + i*8][tx] = (bf16)(v * scl);
    }
    __syncthreads();
    #pragma unroll
    for (int i = 0; i < 4; i++)
        dst[(size_t)(n0 + ty + i*8) * 512 + c0 + tx] = tile[tx][ty + i*8];
}

// ---------------- depthwise 4x4/s3 conv + LayerNorm ----------------
__global__ __launch_bounds__(256) void sr_ln(
    const void* __restrict__ qraw, const bf16* __restrict__ qc,
    const bf16* __restrict__ sm, bf16* __restrict__ x,
    const int* __restrict__ flag)
{
    const bf16* q = (*flag) ? qc : (const bf16*)qraw;
    const bf16* srw  = sm + SM_SRW;
    const bf16* srb  = sm + SM_SRB;
    const bf16* g    = sm + SM_LNG;
    const bf16* beta = sm + SM_LNB;
    int bo = blockIdx.x;
    int b  = bo >> 8, ok = bo & 255;
    int oh = ok >> 4, ow = ok & 15;
    int t  = threadIdx.x;

    float v[2];
    #pragma unroll
    for (int h = 0; h < 2; h++) {
        int ch = t + h*256;
        float acc = 0.f;
        #pragma unroll
        for (int kh = 0; kh < 4; kh++) {
            int ih = oh*3 - 1 + kh;
            if (ih < 0) continue;
            #pragma unroll
            for (int kw = 0; kw < 4; kw++) {
                int iw = ow*3 - 1 + kw;
                if (iw < 0) continue;
                acc += (float)q[((size_t)b*NQ + ih*48 + iw)*DD + ch]
                     * (float)srw[ch*16 + kh*4 + kw];
            }
        }
        v[h] = acc + (float)srb[ch];
    }
    float s = v[0] + v[1], s2 = v[0]*v[0] + v[1]*v[1];
    #pragma unroll
    for (int m = 1; m < 64; m <<= 1) { s += __shfl_xor(s, m); s2 += __shfl_xor(s2, m); }
    __shared__ float ps[4], ps2[4];
    if ((t & 63) == 0) { ps[t >> 6] = s; ps2[t >> 6] = s2; }
    __syncthreads();
    s  = ps[0] + ps[1] + ps[2] + ps[3];
    s2 = ps2[0] + ps2[1] + ps2[2] + ps2[3];
    float mu  = s * (1.f/512.f);
    float var = s2 * (1.f/512.f) - mu*mu;
    float inv = rsqrtf(var + 1e-5f);
    #pragma unroll
    for (int h = 0; h < 2; h++) {
        int ch = t + h*256;
        float y = (v[h] - mu) * inv * (float)g[ch] + (float)beta[ch];
        x[(size_t)bo * DD + ch] = (bf16)y;
    }
}

// ---------------- generic BT-GEMM ----------------
template <int MODE>
__global__ __launch_bounds__(256) void gemm_bt(
    const bf16* __restrict__ A, const bf16* __restrict__ Bt,
    const bf16* __restrict__ bias, bf16* __restrict__ C,
    const int* __restrict__ of32, const bf16* __restrict__ A2)
{
    constexpr int K = 512;
    __shared__ bf16 Al[128 * 64];
    __shared__ bf16 Bl[128 * 64];
    const int m0 = blockIdx.x * 128, n0 = blockIdx.y * 128;
    const int t = threadIdx.x;
    const int lane = t & 63, w = t >> 6;
    const int wr = w >> 1, wc = w & 1;
    const int gg = lane >> 4, li = lane & 15;
    const int fsw = (li & 7) << 4;
    bool f32o = false;
    if (MODE == 2) f32o = (*of32 != 0);

    const bf16* Ab = A;
    if (MODE == 4) Ab = (*of32) ? A2 : A;
    const bf16* Btb = Bt;
    if (MODE == 2) Btb = Bt + (size_t)(m0 / 2304) * (512 * 512);

    f32x4 acc[4][4] = {};

    for (int k0 = 0; k0 < K; k0 += 64) {
        #pragma unroll
        for (int p = 0; p < 4; p++) {
            int off = p*4096 + t*16;
            int row = off >> 7;
            int col = ((((off >> 4) & 7) ^ (row & 7)) << 3);
            gload_lds16(Ab + (size_t)(m0 + row)*K + k0 + col, (char*)Al + off);
        }
        #pragma unroll
        for (int p = 0; p < 4; p++) {
            int off = p*4096 + t*16;
            int row = off >> 7;
            int col = ((((off >> 4) & 7) ^ (row & 7)) << 3);
            gload_lds16(Btb + (size_t)(n0 + row)*K + k0 + col, (char*)Bl + off);
        }
        __syncthreads();
        #pragma unroll
        for (int kk = 0; kk < 2; kk++) {
            bf16x8 af[4], bfr[4];
            #pragma unroll
            for (int i = 0; i < 4; i++) {
                af[i]  = *(const bf16x8*)((char*)Al + (wr*64 + i*16 + li)*128 + ((kk*64 + gg*16) ^ fsw));
                bfr[i] = *(const bf16x8*)((char*)Bl + (wc*64 + i*16 + li)*128 + ((kk*64 + gg*16) ^ fsw));
            }
            __builtin_amdgcn_s_setprio(1);
            #pragma unroll
            for (int i = 0; i < 4; i++)
                #pragma unroll
                for (int j = 0; j < 4; j++)
                    acc[i][j] = __builtin_amdgcn_mfma_f32_16x16x32_bf16(af[i], bfr[j], acc[i][j], 0, 0, 0);
            __builtin_amdgcn_s_setprio(0);
        }
        __syncthreads();
    }

    #pragma unroll
    for (int i = 0; i < 4; i++) {
        #pragma unroll
        for (int j = 0; j < 4; j++) {
            int rbase = m0 + wr*64 + i*16 + gg*4;
            int c     = n0 + wc*64 + j*16 + li;
            float bv = (float)bias[c];
            #pragma unroll
            for (int jj = 0; jj < 4; jj++) {
                float val = acc[i][j][jj] + bv;
                int r = rbase + jj;
                if (MODE == 1) {
                    int bb = r >> 8, kk2 = r & 255;
                    int hh = c >> 6, dv = c & 63;
                    C[(((size_t)(bb*8 + hh))*64 + dv)*256 + kk2] = (bf16)val;
                } else if (MODE == 2) {
                    if (f32o) ((float*)C)[(size_t)r * 512 + c] = val;
                    else      C[(size_t)r * 512 + c] = (bf16)val;
                } else {
                    C[(size_t)r * 512 + c] = (bf16)val;
                }
            }
        }
    }
}

// ---------------- fused S-GEMM + mix + softmax + dev + ssq (v2) ----------------
// grid (144, CB). 512 threads = 8 waves; wave w owns k-band [w*32, w*32+32).
// All accumulators are NAMED scalars (no runtime-indexable arrays).
__global__ __launch_bounds__(512, 2) void gemm_s_mix(
    const bf16* __restrict__ Qf, const bf16* __restrict__ Kt,
    const float* __restrict__ twf, bf16* __restrict__ Dev,
    float* __restrict__ ssq_g, int b0)
{
    __shared__ bf16 Ql[16 * 512];        // 16 KB
    __shared__ bf16 Kl[256 * 64];        // 32 KB
    __shared__ float srow[8 * 16 * 8];   // 4 KB
    __shared__ float rpar[8][8];

    const int t = threadIdx.x;
    const int lane = t & 63, w = t >> 6;
    const int gg = lane >> 4, li = lane & 15;
    const int fsw8 = (li & 7) << 4;
    const int bl = blockIdx.y;
    const int b  = b0 + bl;
    const int q0 = blockIdx.x * 16;

    // stage Q (16x512), swizzled
    #pragma unroll
    for (int p = 0; p < 2; p++) {
        int off = p*8192 + t*16;
        int q = off >> 10, slot = (off >> 4) & 63;
        gload_lds16(Qf + ((size_t)(b*NQ + q0 + q))*DD + ((slot ^ (q & 7)) << 3),
                    (char*)Ql + off);
    }

#define STAGEK(hi) do { \
        _Pragma("unroll") \
        for (int p = 0; p < 4; p++) { \
            int off = p*8192 + t*16; \
            int kr = off >> 7, slot = (off >> 4) & 7; \
            gload_lds16(Kt + ((size_t)(b*NKV + kr))*DD + (hi)*64 + ((slot ^ (kr & 7)) << 3), \
                        (char*)Kl + off); \
        } } while (0)

#define QKCOMP(i, AA0, AA1) do { \
        _Pragma("unroll") \
        for (int kk = 0; kk < 2; kk++) { \
            bf16x8 af = *(const bf16x8*)((char*)Ql + li*1024 + (((i)*128 + kk*64 + gg*16) ^ fsw8)); \
            int kr0 = w*32 + li; \
            bf16x8 bv0 = *(const bf16x8*)((char*)Kl + kr0*128 + ((kk*64 + gg*16) ^ ((kr0 & 7) << 4))); \
            AA0 = __builtin_amdgcn_mfma_f32_16x16x32_bf16(af, bv0, AA0, 0, 0, 0); \
            int kr1 = w*32 + 16 + li; \
            bf16x8 bv1 = *(const bf16x8*)((char*)Kl + kr1*128 + ((kk*64 + gg*16) ^ ((kr1 & 7) << 4))); \
            AA1 = __builtin_amdgcn_mfma_f32_16x16x32_bf16(af, bv1, AA1, 0, 0, 0); \
        } } while (0)

    f32x4 A00 = {}, A01 = {}, A10 = {}, A11 = {}, A20 = {}, A21 = {}, A30 = {}, A31 = {};
    f32x4 A40 = {}, A41 = {}, A50 = {}, A51 = {}, A60 = {}, A61 = {}, A70 = {}, A71 = {};

    STAGEK(0); __syncthreads(); QKCOMP(0, A00, A01);
    __syncthreads(); STAGEK(1); __syncthreads(); QKCOMP(1, A10, A11);
    __syncthreads(); STAGEK(2); __syncthreads(); QKCOMP(2, A20, A21);
    __syncthreads(); STAGEK(3); __syncthreads(); QKCOMP(3, A30, A31);
    __syncthreads(); STAGEK(4); __syncthreads(); QKCOMP(4, A40, A41);
    __syncthreads(); STAGEK(5); __syncthreads(); QKCOMP(5, A50, A51);
    __syncthreads(); STAGEK(6); __syncthreads(); QKCOMP(6, A60, A61);
    __syncthreads(); STAGEK(7); __syncthreads(); QKCOMP(7, A70, A71);
    // element (i, nt, r) = S_i at (q = q0+gg*4+r, k = w*32+nt*16+li)

#define MIX0(r) (two[0]*A00[r]+two[1]*A10[r]+two[2]*A20[r]+two[3]*A30[r]+ \
                 two[4]*A40[r]+two[5]*A50[r]+two[6]*A60[r]+two[7]*A70[r])
#define MIX1(r) (two[0]*A01[r]+two[1]*A11[r]+two[2]*A21[r]+two[3]*A31[r]+ \
                 two[4]*A41[r]+two[5]*A51[r]+two[6]*A61[r]+two[7]*A71[r])

    // pass 1: mix + exp + rowsum partials
    #pragma unroll
    for (int o = 0; o < 8; o++) {
        float two[8];
        #pragma unroll
        for (int i2 = 0; i2 < 8; i2++) two[i2] = twf[o*8 + i2];
        #pragma unroll
        for (int r = 0; r < 4; r++) {
            float a0 = fminf(fmaxf(MIX0(r), -30.f), 30.f);
            float a1 = fminf(fmaxf(MIX1(r), -30.f), 30.f);
            float s = __expf(a0) + __expf(a1);
            s += __shfl_xor(s, 1); s += __shfl_xor(s, 2);
            s += __shfl_xor(s, 4); s += __shfl_xor(s, 8);
            if (li == 0) srow[(o*16 + gg*4 + r)*8 + w] = s;
        }
    }
    __syncthreads();

    // pass 2: recompute exp, normalize, dev, ssq, write Dev
    float ssqL[8];
    #pragma unroll
    for (int o = 0; o < 8; o++) ssqL[o] = 0.f;
    #pragma unroll
    for (int o = 0; o < 8; o++) {
        float two[8];
        #pragma unroll
        for (int i2 = 0; i2 < 8; i2++) two[i2] = twf[o*8 + i2];
        bf16* Dp = Dev + ((size_t)(bl*8 + o))*NQ*NKV;
        #pragma unroll
        for (int r = 0; r < 4; r++) {
            int q = gg*4 + r;
            f32x4 s0 = *(const f32x4*)&srow[(o*16 + q)*8];
            f32x4 s1 = *(const f32x4*)&srow[(o*16 + q)*8 + 4];
            float inv = 1.0f / (s0[0]+s0[1]+s0[2]+s0[3]+s1[0]+s1[1]+s1[2]+s1[3]);
            float a0 = fminf(fmaxf(MIX0(r), -30.f), 30.f);
            float d0 = __expf(a0) * inv - (1.0f/256.0f);
            ssqL[o] += d0 * d0;
            Dp[(size_t)(q0 + q)*NKV + w*32 + li] = (bf16)d0;
            float a1 = fminf(fmaxf(MIX1(r), -30.f), 30.f);
            float d1 = __expf(a1) * inv - (1.0f/256.0f);
            ssqL[o] += d1 * d1;
            Dp[(size_t)(q0 + q)*NKV + w*32 + 16 + li] = (bf16)d1;
        }
    }
    #pragma unroll
    for (int o = 0; o < 8; o++) {
        float s = ssqL[o];
        #pragma unroll
        for (int m = 1; m < 64; m <<= 1) s += __shfl_xor(s, m);
        if (lane == 0) rpar[w][o] = s;
    }
    __syncthreads();
    if (t < 8) {
        float tot = 0.f;
        #pragma unroll
        for (int i = 0; i < 8; i++) tot += rpar[i][t];
        atomicAdd(&ssq_g[b*8 + t], tot);
    }
#undef STAGEK
#undef QKCOMP
#undef MIX0
#undef MIX1
}

// ---------------- PV-GEMM: U[b,o-cols] = Dev[plane] @ V[b,o] ----------------
__global__ __launch_bounds__(256) void gemm_pv(
    const bf16* __restrict__ Dev, const bf16* __restrict__ VT, bf16* __restrict__ U,
    int b0)
{
    __shared__ bf16 Al[128 * 64];
    __shared__ bf16 Bl[64 * 64];
    const int m0 = blockIdx.x * 128;
    const int bo = blockIdx.y;
    const int b = b0 + (bo >> 3), o = bo & 7;
    const int t = threadIdx.x;
    const int lane = t & 63, w = t >> 6;
    const int wr = w >> 1, wc = w & 1;
    const int gg = lane >> 4, li = lane & 15;
    const int fsw = (li & 7) << 4;

    const bf16* Ab = Dev + (size_t)bo * NQ * NKV;
    const bf16* Bb = VT + ((size_t)(b*8 + o)) * 64 * NKV;

    f32x4 acc[4][2] = {};

    for (int k0 = 0; k0 < 256; k0 += 64) {
        #pragma unroll
        for (int p = 0; p < 4; p++) {
            int off = p*4096 + t*16;
            int row = off >> 7;
            int col = ((((off >> 4) & 7) ^ (row & 7)) << 3);
            gload_lds16(Ab + (size_t)(m0 + row)*NKV + k0 + col, (char*)Al + off);
        }
        #pragma unroll
        for (int p = 0; p < 2; p++) {
            int off = p*4096 + t*16;
            int row = off >> 7;
            int col = ((((off >> 4) & 7) ^ (row & 7)) << 3);
            gload_lds16(Bb + (size_t)row*NKV + k0 + col, (char*)Bl + off);
        }
        __syncthreads();
        #pragma unroll
        for (int kk = 0; kk < 2; kk++) {
            bf16x8 af[4], bfr[2];
            #pragma unroll
            for (int i = 0; i < 4; i++)
                af[i] = *(const bf16x8*)((char*)Al + (wr*64 + i*16 + li)*128 + ((kk*64 + gg*16) ^ fsw));
            #pragma unroll
            for (int j = 0; j < 2; j++)
                bfr[j] = *(const bf16x8*)((char*)Bl + (wc*32 + j*16 + li)*128 + ((kk*64 + gg*16) ^ fsw));
            __builtin_amdgcn_s_setprio(1);
            #pragma unroll
            for (int i = 0; i < 4; i++)
                #pragma unroll
                for (int j = 0; j < 2; j++)
                    acc[i][j] = __builtin_amdgcn_mfma_f32_16x16x32_bf16(af[i], bfr[j], acc[i][j], 0, 0, 0);
            __builtin_amdgcn_s_setprio(0);
        }
        __syncthreads();
    }

    #pragma unroll
    for (int i = 0; i < 4; i++) {
        #pragma unroll
        for (int j = 0; j < 2; j++) {
            int rbase = m0 + wr*64 + i*16 + gg*4;
            int c = wc*32 + j*16 + li;
            #pragma unroll
            for (int jj = 0; jj < 4; jj++)
                U[((size_t)b*NQ + rbase + jj)*DD + o*64 + c] = (bf16)acc[i][j][jj];
        }
    }
}

// ---------------- per-batch scaled Wo^T ----------------
__global__ __launch_bounds__(256) void scale_wot(const bf16* __restrict__ WoT,
                                                 const float* __restrict__ ssq,
                                                 bf16* __restrict__ out)
{
    int idx = blockIdx.x * 256 + threadIdx.x;
    int c8 = idx & 63;
    int c  = (idx >> 6) & 511;
    int b  = idx >> 15;
    int h  = c8 >> 3;
    float va = ssq[b*8 + h] * (1.0f / ((float)NQ * (float)NKV));
    float s  = rsqrtf(va + 1e-5f);
    bf16x8 v = *(const bf16x8*)(WoT + ((size_t)c << 9) + c8*8);
    bf16x8 r;
    #pragma unroll
    for (int i = 0; i < 8; i++) r[i] = (bf16)((float)v[i] * s);
    *(bf16x8*)(out + ((size_t)idx << 3)) = r;
}

// ======================================================================
extern "C" void kernel_launch(void* const* d_in, const int* in_sizes, int n_in,
                              void* d_out, int out_size, void* d_ws, size_t ws_size,
                              hipStream_t stream)
{
    const void* queries = d_in[0];
    const void* Wq = d_in[1];  const void* bq = d_in[2];
    const void* Wk = d_in[3];  const void* bk = d_in[4];
    const void* Wv = d_in[5];  const void* bv = d_in[6];
    const void* Wo = d_in[7];  const void* bo = d_in[8];
    const void* srw = d_in[9]; const void* srb = d_in[10];
    const void* lng = d_in[11]; const void* lnb = d_in[12];
    const void* tw  = d_in[13];
    // d_in[14] = tb: cancels in softmax; unused.

    char* ws = (char*)d_ws;
    bf16* WqT = (bf16*)(ws + OFF_WQT);
    bf16* WkT = (bf16*)(ws + OFF_WKT);
    bf16* WvT = (bf16*)(ws + OFF_WVT);
    bf16* WoT = (bf16*)(ws + OFF_WOT);
    bf16* xb  = (bf16*)(ws + OFF_X);
    bf16* Kt  = (bf16*)(ws + OFF_KT);
    bf16* VTb = (bf16*)(ws + OFF_VT);
    bf16* Qf  = (bf16*)(ws + OFF_QF);
    bf16* Ub  = (bf16*)(ws + OFF_U);
    float* ss = (float*)(ws + OFF_SS);
    bf16* sm  = (bf16*)(ws + OFF_SM);
    float* twf = (float*)(ws + OFF_TWF);
    int* flag = (int*)(ws + OFF_FLG);
    bf16* WoTp = (bf16*)(ws + OFF_WOTP);
    bf16* Sb  = (bf16*)(ws + OFF_S);       // Dev chunk buffer
    bf16* Qc  = Ub;                        // converted queries (f32 path)

    int CB = 1;
    if      (OFF_S + 16*8*SPLANE <= ws_size) CB = 16;
    else if (OFF_S +  8*8*SPLANE <= ws_size) CB = 8;
    else if (OFF_S +  4*8*SPLANE <= ws_size) CB = 4;
    else if (OFF_S +  2*8*SPLANE <= ws_size) CB = 2;

    detect_dtype<<<dim3(1), dim3(64), 0, stream>>>((const uint32_t*)queries, flag);
    hipMemsetAsync(ss, 0, 128 * sizeof(float), stream);

    convert_q<<<dim3(9216), dim3(256), 0, stream>>>(queries, Qc, flag);
    convert_small<<<dim3(9), dim3(256), 0, stream>>>(bq, bk, bv, bo, srw, srb, lng, lnb, tw, sm, twf, flag);
    transpose512<<<dim3(16, 16, 4), dim3(32, 8), 0, stream>>>(Wq, Wk, Wv, Wo, WqT, WkT, WvT, WoT, flag);

    sr_ln<<<dim3(NB * NKV), dim3(256), 0, stream>>>(queries, Qc, sm, xb, flag);
    gemm_bt<0><<<dim3(32, 4), dim3(256), 0, stream>>>(xb, WkT, sm + SM_BK, Kt, nullptr, nullptr);
    gemm_bt<1><<<dim3(32, 4), dim3(256), 0, stream>>>(xb, WvT, sm + SM_BV, VTb, nullptr, nullptr);
    gemm_bt<4><<<dim3(288, 4), dim3(256), 0, stream>>>((const bf16*)queries, WqT, sm + SM_BQ, Qf, flag, Qc);

    for (int b0 = 0; b0 < NB; b0 += CB) {
        gemm_s_mix<<<dim3(144, CB), dim3(512), 0, stream>>>(Qf, Kt, twf, Sb, ss, b0);
        gemm_pv<<<dim3(18, CB*8), dim3(256), 0, stream>>>(Sb, VTb, Ub, b0);
    }

    scale_wot<<<dim3(2048), dim3(256), 0, stream>>>(WoT, ss, WoTp);
    gemm_bt<2><<<dim3(288, 4), dim3(256), 0, stream>>>(Ub, WoTp, sm + SM_BO, (bf16*)d_out, flag, nullptr);
}

// Round 10
// 397.337 us; speedup vs baseline: 1.0452x; 1.0452x over previous
//
#include <hip/hip_runtime.h>
#include <hip/hip_bf16.h>
#include <stdint.h>

// ======================================================================
// EMSA fused pipeline. Device dtype (bf16 vs f32) detected at runtime.
// Algebra:
//  * S_i = Q_i K_i^T /8 once per input head (9.7 GF); head-mix tw applied
//    in a streaming VALU kernel; PV is a clean batched GEMM.
//  * softmax row-sums are 1  =>  instance-norm mean = 1/256 exactly
//  * Dev = P - 1/256; var = mean(Dev^2); out = (Dev@V)*rsqrt(va+eps)
//  * tb cancels in softmax; 1/sqrt(dk) folded into WqT/bq;
//    instance-norm scale folded into per-batch pre-scaled Wo^T.
// R10: reverted to the R7 3-kernel attn split (fusion is occupancy-capped:
//     140 unified regs -> 1 block/CU -> serial barriers; R8/R9 both 194us).
//     mix_softmax v2: bf16x8 I/O, 32-lane rows, single pass per head.
// ======================================================================

typedef __bf16 bf16;
typedef __bf16 bf16x4 __attribute__((ext_vector_type(4)));
typedef __bf16 bf16x8 __attribute__((ext_vector_type(8)));
typedef float  f32x4  __attribute__((ext_vector_type(4)));

#define LDS_AS  __attribute__((address_space(3)))
#define GLOB_AS __attribute__((address_space(1)))

__device__ __forceinline__ void gload_lds16(const bf16* g, void* l) {
    __builtin_amdgcn_global_load_lds((const GLOB_AS void*)g, (LDS_AS void*)l, 16, 0, 0);
}

// ---------------- constants ----------------
#define NB   16
#define NQ   2304
#define DD   512
#define NKV  256

// workspace layout (bytes)
constexpr size_t OFF_WQT = 0;
constexpr size_t OFF_WKT = 512*512*2;
constexpr size_t OFF_WVT = 2*512*512*2;
constexpr size_t OFF_WOT = 3*512*512*2;
constexpr size_t OFF_X   = 4*512*512*2;
constexpr size_t OFF_KT  = OFF_X  + 4194304;
constexpr size_t OFF_VT  = OFF_KT + 4194304;
constexpr size_t OFF_SS  = OFF_VT + 4194304;
constexpr size_t OFF_SM  = OFF_SS + 512;
constexpr size_t OFF_TWF = OFF_SM + 24064;
constexpr size_t OFF_FLG = OFF_TWF + 256;
constexpr size_t OFF_QF  = OFF_FLG + 256;
constexpr size_t OFF_U   = OFF_QF + (size_t)NB*NQ*DD*2;
constexpr size_t OFF_S   = OFF_U  + (size_t)NB*NQ*DD*2;   // S/Dev chunk buffer
constexpr size_t SPLANE  = (size_t)NQ*NKV*2;
constexpr size_t OFF_WOTP = OFF_X;   // aliases X+KT (dead by scale_wot)

// small-region element offsets
#define SM_BQ  0
#define SM_BK  512
#define SM_BV  1024
#define SM_BO  1536
#define SM_SRW 2048
#define SM_SRB 10240
#define SM_LNG 10752
#define SM_LNB 11264
#define SM_TW  11776

// ---------------- dtype detection ----------------
__global__ __launch_bounds__(64) void detect_dtype(const uint32_t* __restrict__ q,
                                                   int* __restrict__ flag)
{
    int t = threadIdx.x;
    int cnt = 0;
    #pragma unroll
    for (int i = 0; i < 8; i++) {
        uint32_t w = q[t*8 + i];
        int e = (w >> 7) & 0xFF;
        cnt += (e >= 100 && e <= 150) ? 1 : 0;
    }
    #pragma unroll
    for (int m = 1; m < 64; m <<= 1) cnt += __shfl_xor(cnt, m);
    if (t == 0) *flag = (cnt >= 384) ? 0 : 1;   // 0=bf16, 1=f32
}

// ---------------- input conversion (work only for f32 input) ----------------
__global__ __launch_bounds__(256) void convert_q(const void* __restrict__ in,
                                                 bf16* __restrict__ out,
                                                 const int* __restrict__ flag)
{
    if (*flag == 0) return;
    int idx = blockIdx.x * 256 + threadIdx.x;
    f32x4 a = ((const f32x4*)in)[(size_t)idx*2];
    f32x4 b = ((const f32x4*)in)[(size_t)idx*2 + 1];
    bf16x8 r;
    #pragma unroll
    for (int i = 0; i < 4; i++) { r[i] = (bf16)a[i]; r[i+4] = (bf16)b[i]; }
    ((bf16x8*)out)[idx] = r;
}

__global__ __launch_bounds__(256) void convert_small(
    const void* s0, const void* s1, const void* s2, const void* s3,
    const void* s4, const void* s5, const void* s6, const void* s7,
    const void* s8, bf16* __restrict__ dst, float* __restrict__ twf,
    const int* __restrict__ flag)
{
    const void* srcs[9] = {s0,s1,s2,s3,s4,s5,s6,s7,s8};
    const int sizes[9]  = {512,512,512,512,8192,512,512,512,64};
    const int offs[9]   = {SM_BQ,SM_BK,SM_BV,SM_BO,SM_SRW,SM_SRB,SM_LNG,SM_LNB,SM_TW};
    const float scl[9]  = {0.125f,1.f,1.f,1.f,1.f,1.f,1.f,1.f,1.f};
    int b = blockIdx.x;
    const void* s = srcs[b];
    int n = sizes[b], o = offs[b];
    float sc = scl[b];
    bool f32 = (*flag != 0);
    for (int i = threadIdx.x; i < n; i += 256) {
        float v = f32 ? ((const float*)s)[i] : (float)((const bf16*)s)[i];
        dst[o + i] = (bf16)(v * sc);
        if (b == 8) twf[i] = v;
    }
}

// ---------------- weight transpose (512x512) ----------------
__global__ __launch_bounds__(256) void transpose512(
    const void* s0, const void* s1, const void* s2, const void* s3,
    bf16* __restrict__ d0, bf16* __restrict__ d1,
    bf16* __restrict__ d2, bf16* __restrict__ d3,
    const int* __restrict__ flag)
{
    __shared__ bf16 tile[32][33];
    bool f32 = (*flag != 0);
    int wsel = blockIdx.z;
    const void* src = wsel == 0 ? s0 : wsel == 1 ? s1 : wsel == 2 ? s2 : s3;
    bf16*       dst = wsel == 0 ? d0 : wsel == 1 ? d1 : wsel == 2 ? d2 : d3;
    float scl = (wsel == 0) ? 0.125f : 1.0f;
    int c0 = blockIdx.x * 32, n0 = blockIdx.y * 32;
    int tx = threadIdx.x, ty = threadIdx.y;
    #pragma unroll
    for (int i = 0; i < 4; i++) {
        size_t idx = (size_t)(c0 + ty + i*8) * 512 + n0 + tx;
        float v = f32 ? ((const float*)src)[idx] : (float)((const bf16*)src)[idx];
        tile[ty + i*8][tx] = (bf16)(v * scl);
    }
    __syncthreads();
    #pragma unroll
    for (int i = 0; i < 4; i++)
        dst[(size_t)(n0 + ty + i*8) * 512 + c0 + tx] = tile[tx][ty + i*8];
}

// ---------------- depthwise 4x4/s3 conv + LayerNorm ----------------
__global__ __launch_bounds__(256) void sr_ln(
    const void* __restrict__ qraw, const bf16* __restrict__ qc,
    const bf16* __restrict__ sm, bf16* __restrict__ x,
    const int* __restrict__ flag)
{
    const bf16* q = (*flag) ? qc : (const bf16*)qraw;
    const bf16* srw  = sm + SM_SRW;
    const bf16* srb  = sm + SM_SRB;
    const bf16* g    = sm + SM_LNG;
    const bf16* beta = sm + SM_LNB;
    int bo = blockIdx.x;
    int b  = bo >> 8, ok = bo & 255;
    int oh = ok >> 4, ow = ok & 15;
    int t  = threadIdx.x;

    float v[2];
    #pragma unroll
    for (int h = 0; h < 2; h++) {
        int ch = t + h*256;
        float acc = 0.f;
        #pragma unroll
        for (int kh = 0; kh < 4; kh++) {
            int ih = oh*3 - 1 + kh;
            if (ih < 0) continue;
            #pragma unroll
            for (int kw = 0; kw < 4; kw++) {
                int iw = ow*3 - 1 + kw;
                if (iw < 0) continue;
                acc += (float)q[((size_t)b*NQ + ih*48 + iw)*DD + ch]
                     * (float)srw[ch*16 + kh*4 + kw];
            }
        }
        v[h] = acc + (float)srb[ch];
    }
    float s = v[0] + v[1], s2 = v[0]*v[0] + v[1]*v[1];
    #pragma unroll
    for (int m = 1; m < 64; m <<= 1) { s += __shfl_xor(s, m); s2 += __shfl_xor(s2, m); }
    __shared__ float ps[4], ps2[4];
    if ((t & 63) == 0) { ps[t >> 6] = s; ps2[t >> 6] = s2; }
    __syncthreads();
    s  = ps[0] + ps[1] + ps[2] + ps[3];
    s2 = ps2[0] + ps2[1] + ps2[2] + ps2[3];
    float mu  = s * (1.f/512.f);
    float var = s2 * (1.f/512.f) - mu*mu;
    float inv = rsqrtf(var + 1e-5f);
    #pragma unroll
    for (int h = 0; h < 2; h++) {
        int ch = t + h*256;
        float y = (v[h] - mu) * inv * (float)g[ch] + (float)beta[ch];
        x[(size_t)bo * DD + ch] = (bf16)y;
    }
}

// ---------------- generic BT-GEMM: C(M,512) = A(M,512) @ Bt(512,512)^T + bias ----------
// MODE 0: bf16 row-major store. MODE 1: V^T scatter store (b,h,dv,kk).
// MODE 2: output GEMM (per-batch pre-scaled WoT, dtype-branch store).
// MODE 4: A chosen by flag (raw vs converted queries).
template <int MODE>
__global__ __launch_bounds__(256) void gemm_bt(
    const bf16* __restrict__ A, const bf16* __restrict__ Bt,
    const bf16* __restrict__ bias, bf16* __restrict__ C,
    const int* __restrict__ of32, const bf16* __restrict__ A2)
{
    constexpr int K = 512;
    __shared__ bf16 Al[128 * 64];
    __shared__ bf16 Bl[128 * 64];
    const int m0 = blockIdx.x * 128, n0 = blockIdx.y * 128;
    const int t = threadIdx.x;
    const int lane = t & 63, w = t >> 6;
    const int wr = w >> 1, wc = w & 1;
    const int gg = lane >> 4, li = lane & 15;
    const int fsw = (li & 7) << 4;
    bool f32o = false;
    if (MODE == 2) f32o = (*of32 != 0);

    const bf16* Ab = A;
    if (MODE == 4) Ab = (*of32) ? A2 : A;
    const bf16* Btb = Bt;
    if (MODE == 2) Btb = Bt + (size_t)(m0 / 2304) * (512 * 512);

    f32x4 acc[4][4] = {};

    for (int k0 = 0; k0 < K; k0 += 64) {
        #pragma unroll
        for (int p = 0; p < 4; p++) {
            int off = p*4096 + t*16;
            int row = off >> 7;
            int col = ((((off >> 4) & 7) ^ (row & 7)) << 3);
            gload_lds16(Ab + (size_t)(m0 + row)*K + k0 + col, (char*)Al + off);
        }
        #pragma unroll
        for (int p = 0; p < 4; p++) {
            int off = p*4096 + t*16;
            int row = off >> 7;
            int col = ((((off >> 4) & 7) ^ (row & 7)) << 3);
            gload_lds16(Btb + (size_t)(n0 + row)*K + k0 + col, (char*)Bl + off);
        }
        __syncthreads();
        #pragma unroll
        for (int kk = 0; kk < 2; kk++) {
            bf16x8 af[4], bfr[4];
            #pragma unroll
            for (int i = 0; i < 4; i++) {
                af[i]  = *(const bf16x8*)((char*)Al + (wr*64 + i*16 + li)*128 + ((kk*64 + gg*16) ^ fsw));
                bfr[i] = *(const bf16x8*)((char*)Bl + (wc*64 + i*16 + li)*128 + ((kk*64 + gg*16) ^ fsw));
            }
            __builtin_amdgcn_s_setprio(1);
            #pragma unroll
            for (int i = 0; i < 4; i++)
                #pragma unroll
                for (int j = 0; j < 4; j++)
                    acc[i][j] = __builtin_amdgcn_mfma_f32_16x16x32_bf16(af[i], bfr[j], acc[i][j], 0, 0, 0);
            __builtin_amdgcn_s_setprio(0);
        }
        __syncthreads();
    }

    #pragma unroll
    for (int i = 0; i < 4; i++) {
        #pragma unroll
        for (int j = 0; j < 4; j++) {
            int rbase = m0 + wr*64 + i*16 + gg*4;
            int c     = n0 + wc*64 + j*16 + li;
            float bv = (float)bias[c];
            #pragma unroll
            for (int jj = 0; jj < 4; jj++) {
                float val = acc[i][j][jj] + bv;
                int r = rbase + jj;
                if (MODE == 1) {
                    int bb = r >> 8, kk2 = r & 255;
                    int hh = c >> 6, dv = c & 63;
                    C[(((size_t)(bb*8 + hh))*64 + dv)*256 + kk2] = (bf16)val;
                } else if (MODE == 2) {
                    if (f32o) ((float*)C)[(size_t)r * 512 + c] = val;
                    else      C[(size_t)r * 512 + c] = (bf16)val;
                } else {
                    C[(size_t)r * 512 + c] = (bf16)val;
                }
            }
        }
    }
}

// ---------------- S-GEMM: S[plane] = Q_i @ K_i^T  (M=2304,N=256,K=64) ----------------
__global__ __launch_bounds__(256) void gemm_s(
    const bf16* __restrict__ Qf, const bf16* __restrict__ Kt, bf16* __restrict__ S,
    int b0)
{
    __shared__ bf16 Al[128 * 64];
    __shared__ bf16 Bl[128 * 64];
    const int m0 = blockIdx.x * 128, n0 = blockIdx.y * 128;
    const int bo = blockIdx.z;
    const int b = b0 + (bo >> 3), ih = bo & 7;
    const int t = threadIdx.x;
    const int lane = t & 63, w = t >> 6;
    const int wr = w >> 1, wc = w & 1;
    const int gg = lane >> 4, li = lane & 15;
    const int fsw = (li & 7) << 4;

    #pragma unroll
    for (int p = 0; p < 4; p++) {
        int off = p*4096 + t*16;
        int row = off >> 7;
        int col = ((((off >> 4) & 7) ^ (row & 7)) << 3);
        gload_lds16(Qf + ((size_t)(b*NQ + m0 + row))*DD + ih*64 + col, (char*)Al + off);
    }
    #pragma unroll
    for (int p = 0; p < 4; p++) {
        int off = p*4096 + t*16;
        int row = off >> 7;
        int col = ((((off >> 4) & 7) ^ (row & 7)) << 3);
        gload_lds16(Kt + ((size_t)(b*NKV + n0 + row))*DD + ih*64 + col, (char*)Bl + off);
    }
    __syncthreads();

    f32x4 acc[4][4] = {};
    #pragma unroll
    for (int kk = 0; kk < 2; kk++) {
        bf16x8 af[4], bfr[4];
        #pragma unroll
        for (int i = 0; i < 4; i++) {
            af[i]  = *(const bf16x8*)((char*)Al + (wr*64 + i*16 + li)*128 + ((kk*64 + gg*16) ^ fsw));
            bfr[i] = *(const bf16x8*)((char*)Bl + (wc*64 + i*16 + li)*128 + ((kk*64 + gg*16) ^ fsw));
        }
        __builtin_amdgcn_s_setprio(1);
        #pragma unroll
        for (int i = 0; i < 4; i++)
            #pragma unroll
            for (int j = 0; j < 4; j++)
                acc[i][j] = __builtin_amdgcn_mfma_f32_16x16x32_bf16(af[i], bfr[j], acc[i][j], 0, 0, 0);
        __builtin_amdgcn_s_setprio(0);
    }

    bf16* Sb = S + (size_t)bo * NQ * NKV;
    #pragma unroll
    for (int i = 0; i < 4; i++) {
        #pragma unroll
        for (int j = 0; j < 4; j++) {
            int rbase = m0 + wr*64 + i*16 + gg*4;
            int c     = n0 + wc*64 + j*16 + li;
            #pragma unroll
            for (int jj = 0; jj < 4; jj++)
                Sb[(size_t)(rbase + jj) * NKV + c] = (bf16)acc[i][j][jj];
        }
    }
}

// ---------------- mix + softmax + dev + ssq v2 (streaming, IN-PLACE on S) ----------------
// grid (72, CB); 256 thr = 4 waves. Wave handles 8 q-rows as 4 pairs;
// lane = half*32 + kl: half = row-of-pair, kl covers k = kl*8..+8 (bf16x8).
// Full 256-k row lives in one 32-lane group -> rowsum available in-pass.
__global__ __launch_bounds__(256) void mix_softmax(
    bf16* __restrict__ S, const float* __restrict__ twf,
    float* __restrict__ ssq_g, int b0)
{
    const int t = threadIdx.x;
    const int lane = t & 63, w = t >> 6;
    const int half = lane >> 5, kl = lane & 31;
    const int bl = blockIdx.y;
    const int b  = b0 + bl;
    const int q0 = blockIdx.x * 32 + w * 8;
    __shared__ float rpar[4][8];

    float tw[8][8];
    #pragma unroll
    for (int o = 0; o < 8; o++)
        #pragma unroll
        for (int i = 0; i < 8; i++)
            tw[o][i] = twf[o*8 + i];     // uniform address -> scalar load

    float ssqL[8] = {};
    #pragma unroll
    for (int qi = 0; qi < 4; qi++) {
        const int q = q0 + qi*2 + half;
        float s[8][8];
        #pragma unroll
        for (int i = 0; i < 8; i++) {
            bf16x8 v = *(const bf16x8*)(S + (((size_t)(bl*8 + i))*NQ + q)*NKV + kl*8);
            #pragma unroll
            for (int r = 0; r < 8; r++) s[i][r] = (float)v[r];
        }
        #pragma unroll
        for (int o = 0; o < 8; o++) {
            float e[8];
            float sum = 0.f;
            #pragma unroll
            for (int r = 0; r < 8; r++) {
                float a = tw[o][0]*s[0][r] + tw[o][1]*s[1][r] + tw[o][2]*s[2][r]
                        + tw[o][3]*s[3][r] + tw[o][4]*s[4][r] + tw[o][5]*s[5][r]
                        + tw[o][6]*s[6][r] + tw[o][7]*s[7][r];
                a = fminf(fmaxf(a, -30.f), 30.f);
                e[r] = __expf(a);
                sum += e[r];
            }
            sum += __shfl_xor(sum, 1);  sum += __shfl_xor(sum, 2);
            sum += __shfl_xor(sum, 4);  sum += __shfl_xor(sum, 8);
            sum += __shfl_xor(sum, 16);
            float inv = 1.0f / sum;
            bf16x8 dv;
            #pragma unroll
            for (int r = 0; r < 8; r++) {
                float d = e[r] * inv - (1.0f/256.0f);
                ssqL[o] += d * d;
                dv[r] = (bf16)d;
            }
            *(bf16x8*)(S + (((size_t)(bl*8 + o))*NQ + q)*NKV + kl*8) = dv;
        }
    }
    #pragma unroll
    for (int o = 0; o < 8; o++) {
        float s = ssqL[o];
        #pragma unroll
        for (int m = 1; m < 64; m <<= 1) s += __shfl_xor(s, m);
        if (lane == 0) rpar[w][o] = s;
    }
    __syncthreads();
    if (t < 8) {
        float tot = rpar[0][t] + rpar[1][t] + rpar[2][t] + rpar[3][t];
        atomicAdd(&ssq_g[b*8 + t], tot);
    }
}

// ---------------- PV-GEMM: U[b,o-cols] = Dev[plane] @ V[b,o]  (M=2304,N=64,K=256) ----
__global__ __launch_bounds__(256) void gemm_pv(
    const bf16* __restrict__ Dev, const bf16* __restrict__ VT, bf16* __restrict__ U,
    int b0)
{
    __shared__ bf16 Al[128 * 64];
    __shared__ bf16 Bl[64 * 64];
    const int m0 = blockIdx.x * 128;
    const int bo = blockIdx.y;
    const int b = b0 + (bo >> 3), o = bo & 7;
    const int t = threadIdx.x;
    const int lane = t & 63, w = t >> 6;
    const int wr = w >> 1, wc = w & 1;
    const int gg = lane >> 4, li = lane & 15;
    const int fsw = (li & 7) << 4;

    const bf16* Ab = Dev + (size_t)bo * NQ * NKV;
    const bf16* Bb = VT + ((size_t)(b*8 + o)) * 64 * NKV;

    f32x4 acc[4][2] = {};

    for (int k0 = 0; k0 < 256; k0 += 64) {
        #pragma unroll
        for (int p = 0; p < 4; p++) {
            int off = p*4096 + t*16;
            int row = off >> 7;
            int col = ((((off >> 4) & 7) ^ (row & 7)) << 3);
            gload_lds16(Ab + (size_t)(m0 + row)*NKV + k0 + col, (char*)Al + off);
        }
        #pragma unroll
        for (int p = 0; p < 2; p++) {
            int off = p*4096 + t*16;
            int row = off >> 7;
            int col = ((((off >> 4) & 7) ^ (row & 7)) << 3);
            gload_lds16(Bb + (size_t)row*NKV + k0 + col, (char*)Bl + off);
        }
        __syncthreads();
        #pragma unroll
        for (int kk = 0; kk < 2; kk++) {
            bf16x8 af[4], bfr[2];
            #pragma unroll
            for (int i = 0; i < 4; i++)
                af[i] = *(const bf16x8*)((char*)Al + (wr*64 + i*16 + li)*128 + ((kk*64 + gg*16) ^ fsw));
            #pragma unroll
            for (int j = 0; j < 2; j++)
                bfr[j] = *(const bf16x8*)((char*)Bl + (wc*32 + j*16 + li)*128 + ((kk*64 + gg*16) ^ fsw));
            __builtin_amdgcn_s_setprio(1);
            #pragma unroll
            for (int i = 0; i < 4; i++)
                #pragma unroll
                for (int j = 0; j < 2; j++)
                    acc[i][j] = __builtin_amdgcn_mfma_f32_16x16x32_bf16(af[i], bfr[j], acc[i][j], 0, 0, 0);
            __builtin_amdgcn_s_setprio(0);
        }
        __syncthreads();
    }

    #pragma unroll
    for (int i = 0; i < 4; i++) {
        #pragma unroll
        for (int j = 0; j < 2; j++) {
            int rbase = m0 + wr*64 + i*16 + gg*4;
            int c = wc*32 + j*16 + li;
            #pragma unroll
            for (int jj = 0; jj < 4; jj++)
                U[((size_t)b*NQ + rbase + jj)*DD + o*64 + c] = (bf16)acc[i][j][jj];
        }
    }
}

// ---------------- per-batch scaled Wo^T ----------------
__global__ __launch_bounds__(256) void scale_wot(const bf16* __restrict__ WoT,
                                                 const float* __restrict__ ssq,
                                                 bf16* __restrict__ out)
{
    int idx = blockIdx.x * 256 + threadIdx.x;
    int c8 = idx & 63;
    int c  = (idx >> 6) & 511;
    int b  = idx >> 15;
    int h  = c8 >> 3;
    float va = ssq[b*8 + h] * (1.0f / ((float)NQ * (float)NKV));
    float s  = rsqrtf(va + 1e-5f);
    bf16x8 v = *(const bf16x8*)(WoT + ((size_t)c << 9) + c8*8);
    bf16x8 r;
    #pragma unroll
    for (int i = 0; i < 8; i++) r[i] = (bf16)((float)v[i] * s);
    *(bf16x8*)(out + ((size_t)idx << 3)) = r;
}

// ======================================================================
extern "C" void kernel_launch(void* const* d_in, const int* in_sizes, int n_in,
                              void* d_out, int out_size, void* d_ws, size_t ws_size,
                              hipStream_t stream)
{
    const void* queries = d_in[0];
    const void* Wq = d_in[1];  const void* bq = d_in[2];
    const void* Wk = d_in[3];  const void* bk = d_in[4];
    const void* Wv = d_in[5];  const void* bv = d_in[6];
    const void* Wo = d_in[7];  const void* bo = d_in[8];
    const void* srw = d_in[9]; const void* srb = d_in[10];
    const void* lng = d_in[11]; const void* lnb = d_in[12];
    const void* tw  = d_in[13];
    // d_in[14] = tb: cancels in softmax; unused.

    char* ws = (char*)d_ws;
    bf16* WqT = (bf16*)(ws + OFF_WQT);
    bf16* WkT = (bf16*)(ws + OFF_WKT);
    bf16* WvT = (bf16*)(ws + OFF_WVT);
    bf16* WoT = (bf16*)(ws + OFF_WOT);
    bf16* xb  = (bf16*)(ws + OFF_X);
    bf16* Kt  = (bf16*)(ws + OFF_KT);
    bf16* VTb = (bf16*)(ws + OFF_VT);
    bf16* Qf  = (bf16*)(ws + OFF_QF);
    bf16* Ub  = (bf16*)(ws + OFF_U);
    float* ss = (float*)(ws + OFF_SS);
    bf16* sm  = (bf16*)(ws + OFF_SM);
    float* twf = (float*)(ws + OFF_TWF);
    int* flag = (int*)(ws + OFF_FLG);
    bf16* WoTp = (bf16*)(ws + OFF_WOTP);
    bf16* Sb  = (bf16*)(ws + OFF_S);       // S/Dev chunk buffer (in-place mix)
    bf16* Qc  = Ub;                        // converted queries (f32 path)

    // chunk size: largest CB whose S buffer fits the workspace
    int CB = 1;
    if      (OFF_S + 16*8*SPLANE <= ws_size) CB = 16;
    else if (OFF_S +  8*8*SPLANE <= ws_size) CB = 8;
    else if (OFF_S +  4*8*SPLANE <= ws_size) CB = 4;
    else if (OFF_S +  2*8*SPLANE <= ws_size) CB = 2;

    detect_dtype<<<dim3(1), dim3(64), 0, stream>>>((const uint32_t*)queries, flag);
    hipMemsetAsync(ss, 0, 128 * sizeof(float), stream);

    convert_q<<<dim3(9216), dim3(256), 0, stream>>>(queries, Qc, flag);
    convert_small<<<dim3(9), dim3(256), 0, stream>>>(bq, bk, bv, bo, srw, srb, lng, lnb, tw, sm, twf, flag);
    transpose512<<<dim3(16, 16, 4), dim3(32, 8), 0, stream>>>(Wq, Wk, Wv, Wo, WqT, WkT, WvT, WoT, flag);

    sr_ln<<<dim3(NB * NKV), dim3(256), 0, stream>>>(queries, Qc, sm, xb, flag);
    gemm_bt<0><<<dim3(32, 4), dim3(256), 0, stream>>>(xb, WkT, sm + SM_BK, Kt, nullptr, nullptr);
    gemm_bt<1><<<dim3(32, 4), dim3(256), 0, stream>>>(xb, WvT, sm + SM_BV, VTb, nullptr, nullptr);
    gemm_bt<4><<<dim3(288, 4), dim3(256), 0, stream>>>((const bf16*)queries, WqT, sm + SM_BQ, Qf, flag, Qc);

    for (int b0 = 0; b0 < NB; b0 += CB) {
        gemm_s<<<dim3(18, 2, CB*8), dim3(256), 0, stream>>>(Qf, Kt, Sb, b0);
        mix_softmax<<<dim3(72, CB), dim3(256), 0, stream>>>(Sb, twf, ss, b0);
        gemm_pv<<<dim3(18, CB*8), dim3(256), 0, stream>>>(Sb, VTb, Ub, b0);
    }

    scale_wot<<<dim3(2048), dim3(256), 0, stream>>>(WoT, ss, WoTp);
    gemm_bt<2><<<dim3(288, 4), dim3(256), 0, stream>>>(Ub, WoTp, sm + SM_BO, (bf16*)d_out, flag, nullptr);
}

// Round 11
// 365.191 us; speedup vs baseline: 1.1372x; 1.0880x over previous
//
#include <hip/hip_runtime.h>
#include <hip/hip_bf16.h>
#include <stdint.h>

// ======================================================================
// EMSA fused pipeline. Device dtype (bf16 vs f32) detected at runtime.
// Algebra:
//  * S_i = Q_i K_i^T /8 once per input head (9.7 GF); head-mix tw applied
//    in a streaming VALU kernel; PV is a clean batched GEMM.
//  * softmax row-sums are 1  =>  instance-norm mean = 1/256 exactly
//  * Dev = P - 1/256; var = mean(Dev^2); out = (Dev@V)*rsqrt(va+eps)
//  * tb cancels in softmax; 1/sqrt(dk) folded into WqT/bq;
//    instance-norm scale folded into per-batch pre-scaled Wo^T.
// R11: mix_softmax reverted to R7's register-lean form (VGPR 48, 70.8us
//     measured) — R10's single-pass v2 hit VGPR 156 / 9.8% occupancy /
//     135us. Clamp dropped (scores bounded). CB=16 -> 8 so the S/Dev
//     chunk (75.5 MB) stays L3-resident across the attn triple.
// ======================================================================

typedef __bf16 bf16;
typedef __bf16 bf16x4 __attribute__((ext_vector_type(4)));
typedef __bf16 bf16x8 __attribute__((ext_vector_type(8)));
typedef float  f32x4  __attribute__((ext_vector_type(4)));

#define LDS_AS  __attribute__((address_space(3)))
#define GLOB_AS __attribute__((address_space(1)))

__device__ __forceinline__ void gload_lds16(const bf16* g, void* l) {
    __builtin_amdgcn_global_load_lds((const GLOB_AS void*)g, (LDS_AS void*)l, 16, 0, 0);
}

// ---------------- constants ----------------
#define NB   16
#define NQ   2304
#define DD   512
#define NKV  256

// workspace layout (bytes)
constexpr size_t OFF_WQT = 0;
constexpr size_t OFF_WKT = 512*512*2;
constexpr size_t OFF_WVT = 2*512*512*2;
constexpr size_t OFF_WOT = 3*512*512*2;
constexpr size_t OFF_X   = 4*512*512*2;
constexpr size_t OFF_KT  = OFF_X  + 4194304;
constexpr size_t OFF_VT  = OFF_KT + 4194304;
constexpr size_t OFF_SS  = OFF_VT + 4194304;
constexpr size_t OFF_SM  = OFF_SS + 512;
constexpr size_t OFF_TWF = OFF_SM + 24064;
constexpr size_t OFF_FLG = OFF_TWF + 256;
constexpr size_t OFF_QF  = OFF_FLG + 256;
constexpr size_t OFF_U   = OFF_QF + (size_t)NB*NQ*DD*2;
constexpr size_t OFF_S   = OFF_U  + (size_t)NB*NQ*DD*2;   // S/Dev chunk buffer
constexpr size_t SPLANE  = (size_t)NQ*NKV*2;
constexpr size_t OFF_WOTP = OFF_X;   // aliases X+KT (dead by scale_wot)

// small-region element offsets
#define SM_BQ  0
#define SM_BK  512
#define SM_BV  1024
#define SM_BO  1536
#define SM_SRW 2048
#define SM_SRB 10240
#define SM_LNG 10752
#define SM_LNB 11264
#define SM_TW  11776

// ---------------- dtype detection ----------------
__global__ __launch_bounds__(64) void detect_dtype(const uint32_t* __restrict__ q,
                                                   int* __restrict__ flag)
{
    int t = threadIdx.x;
    int cnt = 0;
    #pragma unroll
    for (int i = 0; i < 8; i++) {
        uint32_t w = q[t*8 + i];
        int e = (w >> 7) & 0xFF;
        cnt += (e >= 100 && e <= 150) ? 1 : 0;
    }
    #pragma unroll
    for (int m = 1; m < 64; m <<= 1) cnt += __shfl_xor(cnt, m);
    if (t == 0) *flag = (cnt >= 384) ? 0 : 1;   // 0=bf16, 1=f32
}

// ---------------- input conversion (work only for f32 input) ----------------
__global__ __launch_bounds__(256) void convert_q(const void* __restrict__ in,
                                                 bf16* __restrict__ out,
                                                 const int* __restrict__ flag)
{
    if (*flag == 0) return;
    int idx = blockIdx.x * 256 + threadIdx.x;
    f32x4 a = ((const f32x4*)in)[(size_t)idx*2];
    f32x4 b = ((const f32x4*)in)[(size_t)idx*2 + 1];
    bf16x8 r;
    #pragma unroll
    for (int i = 0; i < 4; i++) { r[i] = (bf16)a[i]; r[i+4] = (bf16)b[i]; }
    ((bf16x8*)out)[idx] = r;
}

__global__ __launch_bounds__(256) void convert_small(
    const void* s0, const void* s1, const void* s2, const void* s3,
    const void* s4, const void* s5, const void* s6, const void* s7,
    const void* s8, bf16* __restrict__ dst, float* __restrict__ twf,
    const int* __restrict__ flag)
{
    const void* srcs[9] = {s0,s1,s2,s3,s4,s5,s6,s7,s8};
    const int sizes[9]  = {512,512,512,512,8192,512,512,512,64};
    const int offs[9]   = {SM_BQ,SM_BK,SM_BV,SM_BO,SM_SRW,SM_SRB,SM_LNG,SM_LNB,SM_TW};
    const float scl[9]  = {0.125f,1.f,1.f,1.f,1.f,1.f,1.f,1.f,1.f};
    int b = blockIdx.x;
    const void* s = srcs[b];
    int n = sizes[b], o = offs[b];
    float sc = scl[b];
    bool f32 = (*flag != 0);
    for (int i = threadIdx.x; i < n; i += 256) {
        float v = f32 ? ((const float*)s)[i] : (float)((const bf16*)s)[i];
        dst[o + i] = (bf16)(v * sc);
        if (b == 8) twf[i] = v;
    }
}

// ---------------- weight transpose (512x512) ----------------
__global__ __launch_bounds__(256) void transpose512(
    const void* s0, const void* s1, const void* s2, const void* s3,
    bf16* __restrict__ d0, bf16* __restrict__ d1,
    bf16* __restrict__ d2, bf16* __restrict__ d3,
    const int* __restrict__ flag)
{
    __shared__ bf16 tile[32][33];
    bool f32 = (*flag != 0);
    int wsel = blockIdx.z;
    const void* src = wsel == 0 ? s0 : wsel == 1 ? s1 : wsel == 2 ? s2 : s3;
    bf16*       dst = wsel == 0 ? d0 : wsel == 1 ? d1 : wsel == 2 ? d2 : d3;
    float scl = (wsel == 0) ? 0.125f : 1.0f;
    int c0 = blockIdx.x * 32, n0 = blockIdx.y * 32;
    int tx = threadIdx.x, ty = threadIdx.y;
    #pragma unroll
    for (int i = 0; i < 4; i++) {
        size_t idx = (size_t)(c0 + ty + i*8) * 512 + n0 + tx;
        float v = f32 ? ((const float*)src)[idx] : (float)((const bf16*)src)[idx];
        tile[ty + i*8][tx] = (bf16)(v * scl);
    }
    __syncthreads();
    #pragma unroll
    for (int i = 0; i < 4; i++)
        dst[(size_t)(n0 + ty + i*8) * 512 + c0 + tx] = tile[tx][ty + i*8];
}

// ---------------- depthwise 4x4/s3 conv + LayerNorm ----------------
__global__ __launch_bounds__(256) void sr_ln(
    const void* __restrict__ qraw, const bf16* __restrict__ qc,
    const bf16* __restrict__ sm, bf16* __restrict__ x,
    const int* __restrict__ flag)
{
    const bf16* q = (*flag) ? qc : (const bf16*)qraw;
    const bf16* srw  = sm + SM_SRW;
    const bf16* srb  = sm + SM_SRB;
    const bf16* g    = sm + SM_LNG;
    const bf16* beta = sm + SM_LNB;
    int bo = blockIdx.x;
    int b  = bo >> 8, ok = bo & 255;
    int oh = ok >> 4, ow = ok & 15;
    int t  = threadIdx.x;

    float v[2];
    #pragma unroll
    for (int h = 0; h < 2; h++) {
        int ch = t + h*256;
        float acc = 0.f;
        #pragma unroll
        for (int kh = 0; kh < 4; kh++) {
            int ih = oh*3 - 1 + kh;
            if (ih < 0) continue;
            #pragma unroll
            for (int kw = 0; kw < 4; kw++) {
                int iw = ow*3 - 1 + kw;
                if (iw < 0) continue;
                acc += (float)q[((size_t)b*NQ + ih*48 + iw)*DD + ch]
                     * (float)srw[ch*16 + kh*4 + kw];
            }
        }
        v[h] = acc + (float)srb[ch];
    }
    float s = v[0] + v[1], s2 = v[0]*v[0] + v[1]*v[1];
    #pragma unroll
    for (int m = 1; m < 64; m <<= 1) { s += __shfl_xor(s, m); s2 += __shfl_xor(s2, m); }
    __shared__ float ps[4], ps2[4];
    if ((t & 63) == 0) { ps[t >> 6] = s; ps2[t >> 6] = s2; }
    __syncthreads();
    s  = ps[0] + ps[1] + ps[2] + ps[3];
    s2 = ps2[0] + ps2[1] + ps2[2] + ps2[3];
    float mu  = s * (1.f/512.f);
    float var = s2 * (1.f/512.f) - mu*mu;
    float inv = rsqrtf(var + 1e-5f);
    #pragma unroll
    for (int h = 0; h < 2; h++) {
        int ch = t + h*256;
        float y = (v[h] - mu) * inv * (float)g[ch] + (float)beta[ch];
        x[(size_t)bo * DD + ch] = (bf16)y;
    }
}

// ---------------- generic BT-GEMM: C(M,512) = A(M,512) @ Bt(512,512)^T + bias ----------
// MODE 0: bf16 row-major store. MODE 1: V^T scatter store (b,h,dv,kk).
// MODE 2: output GEMM (per-batch pre-scaled WoT, dtype-branch store).
// MODE 4: A chosen by flag (raw vs converted queries).
template <int MODE>
__global__ __launch_bounds__(256) void gemm_bt(
    const bf16* __restrict__ A, const bf16* __restrict__ Bt,
    const bf16* __restrict__ bias, bf16* __restrict__ C,
    const int* __restrict__ of32, const bf16* __restrict__ A2)
{
    constexpr int K = 512;
    __shared__ bf16 Al[128 * 64];
    __shared__ bf16 Bl[128 * 64];
    const int m0 = blockIdx.x * 128, n0 = blockIdx.y * 128;
    const int t = threadIdx.x;
    const int lane = t & 63, w = t >> 6;
    const int wr = w >> 1, wc = w & 1;
    const int gg = lane >> 4, li = lane & 15;
    const int fsw = (li & 7) << 4;
    bool f32o = false;
    if (MODE == 2) f32o = (*of32 != 0);

    const bf16* Ab = A;
    if (MODE == 4) Ab = (*of32) ? A2 : A;
    const bf16* Btb = Bt;
    if (MODE == 2) Btb = Bt + (size_t)(m0 / 2304) * (512 * 512);

    f32x4 acc[4][4] = {};

    for (int k0 = 0; k0 < K; k0 += 64) {
        #pragma unroll
        for (int p = 0; p < 4; p++) {
            int off = p*4096 + t*16;
            int row = off >> 7;
            int col = ((((off >> 4) & 7) ^ (row & 7)) << 3);
            gload_lds16(Ab + (size_t)(m0 + row)*K + k0 + col, (char*)Al + off);
        }
        #pragma unroll
        for (int p = 0; p < 4; p++) {
            int off = p*4096 + t*16;
            int row = off >> 7;
            int col = ((((off >> 4) & 7) ^ (row & 7)) << 3);
            gload_lds16(Btb + (size_t)(n0 + row)*K + k0 + col, (char*)Bl + off);
        }
        __syncthreads();
        #pragma unroll
        for (int kk = 0; kk < 2; kk++) {
            bf16x8 af[4], bfr[4];
            #pragma unroll
            for (int i = 0; i < 4; i++) {
                af[i]  = *(const bf16x8*)((char*)Al + (wr*64 + i*16 + li)*128 + ((kk*64 + gg*16) ^ fsw));
                bfr[i] = *(const bf16x8*)((char*)Bl + (wc*64 + i*16 + li)*128 + ((kk*64 + gg*16) ^ fsw));
            }
            __builtin_amdgcn_s_setprio(1);
            #pragma unroll
            for (int i = 0; i < 4; i++)
                #pragma unroll
                for (int j = 0; j < 4; j++)
                    acc[i][j] = __builtin_amdgcn_mfma_f32_16x16x32_bf16(af[i], bfr[j], acc[i][j], 0, 0, 0);
            __builtin_amdgcn_s_setprio(0);
        }
        __syncthreads();
    }

    #pragma unroll
    for (int i = 0; i < 4; i++) {
        #pragma unroll
        for (int j = 0; j < 4; j++) {
            int rbase = m0 + wr*64 + i*16 + gg*4;
            int c     = n0 + wc*64 + j*16 + li;
            float bv = (float)bias[c];
            #pragma unroll
            for (int jj = 0; jj < 4; jj++) {
                float val = acc[i][j][jj] + bv;
                int r = rbase + jj;
                if (MODE == 1) {
                    int bb = r >> 8, kk2 = r & 255;
                    int hh = c >> 6, dv = c & 63;
                    C[(((size_t)(bb*8 + hh))*64 + dv)*256 + kk2] = (bf16)val;
                } else if (MODE == 2) {
                    if (f32o) ((float*)C)[(size_t)r * 512 + c] = val;
                    else      C[(size_t)r * 512 + c] = (bf16)val;
                } else {
                    C[(size_t)r * 512 + c] = (bf16)val;
                }
            }
        }
    }
}

// ---------------- S-GEMM: S[plane] = Q_i @ K_i^T  (M=2304,N=256,K=64) ----------------
__global__ __launch_bounds__(256) void gemm_s(
    const bf16* __restrict__ Qf, const bf16* __restrict__ Kt, bf16* __restrict__ S,
    int b0)
{
    __shared__ bf16 Al[128 * 64];
    __shared__ bf16 Bl[128 * 64];
    const int m0 = blockIdx.x * 128, n0 = blockIdx.y * 128;
    const int bo = blockIdx.z;
    const int b = b0 + (bo >> 3), ih = bo & 7;
    const int t = threadIdx.x;
    const int lane = t & 63, w = t >> 6;
    const int wr = w >> 1, wc = w & 1;
    const int gg = lane >> 4, li = lane & 15;
    const int fsw = (li & 7) << 4;

    #pragma unroll
    for (int p = 0; p < 4; p++) {
        int off = p*4096 + t*16;
        int row = off >> 7;
        int col = ((((off >> 4) & 7) ^ (row & 7)) << 3);
        gload_lds16(Qf + ((size_t)(b*NQ + m0 + row))*DD + ih*64 + col, (char*)Al + off);
    }
    #pragma unroll
    for (int p = 0; p < 4; p++) {
        int off = p*4096 + t*16;
        int row = off >> 7;
        int col = ((((off >> 4) & 7) ^ (row & 7)) << 3);
        gload_lds16(Kt + ((size_t)(b*NKV + n0 + row))*DD + ih*64 + col, (char*)Bl + off);
    }
    __syncthreads();

    f32x4 acc[4][4] = {};
    #pragma unroll
    for (int kk = 0; kk < 2; kk++) {
        bf16x8 af[4], bfr[4];
        #pragma unroll
        for (int i = 0; i < 4; i++) {
            af[i]  = *(const bf16x8*)((char*)Al + (wr*64 + i*16 + li)*128 + ((kk*64 + gg*16) ^ fsw));
            bfr[i] = *(const bf16x8*)((char*)Bl + (wc*64 + i*16 + li)*128 + ((kk*64 + gg*16) ^ fsw));
        }
        __builtin_amdgcn_s_setprio(1);
        #pragma unroll
        for (int i = 0; i < 4; i++)
            #pragma unroll
            for (int j = 0; j < 4; j++)
                acc[i][j] = __builtin_amdgcn_mfma_f32_16x16x32_bf16(af[i], bfr[j], acc[i][j], 0, 0, 0);
        __builtin_amdgcn_s_setprio(0);
    }

    bf16* Sb = S + (size_t)bo * NQ * NKV;
    #pragma unroll
    for (int i = 0; i < 4; i++) {
        #pragma unroll
        for (int j = 0; j < 4; j++) {
            int rbase = m0 + wr*64 + i*16 + gg*4;
            int c     = n0 + wc*64 + j*16 + li;
            #pragma unroll
            for (int jj = 0; jj < 4; jj++)
                Sb[(size_t)(rbase + jj) * NKV + c] = (bf16)acc[i][j][jj];
        }
    }
}

// ---------------- mix + softmax + dev + ssq (streaming, IN-PLACE on S) ----------------
// R7 register-lean form (VGPR 48, 65% VALUBusy measured); clamp dropped
// (|scores| bounded << 1 for this op's LN-normalized inputs).
// grid (72, CB); 256 thr = 4 waves; wave handles 8 q-rows; lane covers k=lane*4..+4.
__global__ __launch_bounds__(256) void mix_softmax(
    bf16* __restrict__ S, const float* __restrict__ twf,
    float* __restrict__ ssq_g, int b0)
{
    const int t = threadIdx.x;
    const int lane = t & 63, w = t >> 6;
    const int bl = blockIdx.y;
    const int b  = b0 + bl;
    const int q0 = blockIdx.x * 32 + w * 8;
    __shared__ float rpar[4][8];

    float tw[8][8];
    #pragma unroll
    for (int o = 0; o < 8; o++)
        #pragma unroll
        for (int i = 0; i < 8; i++)
            tw[o][i] = twf[o*8 + i];     // uniform address -> scalar load

    float ssqL[8] = {};
    for (int qi = 0; qi < 8; qi++) {
        float s[8][4];
        #pragma unroll
        for (int i = 0; i < 8; i++) {
            bf16x4 v = *(const bf16x4*)(S + (((size_t)(bl*8 + i))*NQ + (q0 + qi))*NKV + lane*4);
            #pragma unroll
            for (int r = 0; r < 4; r++) s[i][r] = (float)v[r];
        }
        float e[8][4], inv[8];
        #pragma unroll
        for (int o = 0; o < 8; o++) {
            float sum = 0.f;
            #pragma unroll
            for (int r = 0; r < 4; r++) {
                float a = 0.f;
                #pragma unroll
                for (int i = 0; i < 8; i++) a += tw[o][i] * s[i][r];
                e[o][r] = __expf(a);
                sum += e[o][r];
            }
            #pragma unroll
            for (int m = 1; m < 64; m <<= 1) sum += __shfl_xor(sum, m);
            inv[o] = 1.0f / sum;
        }
        #pragma unroll
        for (int o = 0; o < 8; o++) {
            bf16x4 dv;
            #pragma unroll
            for (int r = 0; r < 4; r++) {
                float d = e[o][r] * inv[o] - (1.0f/256.0f);
                ssqL[o] += d * d;
                dv[r] = (bf16)d;
            }
            *(bf16x4*)(S + (((size_t)(bl*8 + o))*NQ + (q0 + qi))*NKV + lane*4) = dv;
        }
    }
    #pragma unroll
    for (int o = 0; o < 8; o++) {
        float s = ssqL[o];
        #pragma unroll
        for (int m = 1; m < 64; m <<= 1) s += __shfl_xor(s, m);
        if (lane == 0) rpar[w][o] = s;
    }
    __syncthreads();
    if (t < 8) {
        float tot = rpar[0][t] + rpar[1][t] + rpar[2][t] + rpar[3][t];
        atomicAdd(&ssq_g[b*8 + t], tot);
    }
}

// ---------------- PV-GEMM: U[b,o-cols] = Dev[plane] @ V[b,o]  (M=2304,N=64,K=256) ----
__global__ __launch_bounds__(256) void gemm_pv(
    const bf16* __restrict__ Dev, const bf16* __restrict__ VT, bf16* __restrict__ U,
    int b0)
{
    __shared__ bf16 Al[128 * 64];
    __shared__ bf16 Bl[64 * 64];
    const int m0 = blockIdx.x * 128;
    const int bo = blockIdx.y;
    const int b = b0 + (bo >> 3), o = bo & 7;
    const int t = threadIdx.x;
    const int lane = t & 63, w = t >> 6;
    const int wr = w >> 1, wc = w & 1;
    const int gg = lane >> 4, li = lane & 15;
    const int fsw = (li & 7) << 4;

    const bf16* Ab = Dev + (size_t)bo * NQ * NKV;
    const bf16* Bb = VT + ((size_t)(b*8 + o)) * 64 * NKV;

    f32x4 acc[4][2] = {};

    for (int k0 = 0; k0 < 256; k0 += 64) {
        #pragma unroll
        for (int p = 0; p < 4; p++) {
            int off = p*4096 + t*16;
            int row = off >> 7;
            int col = ((((off >> 4) & 7) ^ (row & 7)) << 3);
            gload_lds16(Ab + (size_t)(m0 + row)*NKV + k0 + col, (char*)Al + off);
        }
        #pragma unroll
        for (int p = 0; p < 2; p++) {
            int off = p*4096 + t*16;
            int row = off >> 7;
            int col = ((((off >> 4) & 7) ^ (row & 7)) << 3);
            gload_lds16(Bb + (size_t)row*NKV + k0 + col, (char*)Bl + off);
        }
        __syncthreads();
        #pragma unroll
        for (int kk = 0; kk < 2; kk++) {
            bf16x8 af[4], bfr[2];
            #pragma unroll
            for (int i = 0; i < 4; i++)
                af[i] = *(const bf16x8*)((char*)Al + (wr*64 + i*16 + li)*128 + ((kk*64 + gg*16) ^ fsw));
            #pragma unroll
            for (int j = 0; j < 2; j++)
                bfr[j] = *(const bf16x8*)((char*)Bl + (wc*32 + j*16 + li)*128 + ((kk*64 + gg*16) ^ fsw));
            __builtin_amdgcn_s_setprio(1);
            #pragma unroll
            for (int i = 0; i < 4; i++)
                #pragma unroll
                for (int j = 0; j < 2; j++)
                    acc[i][j] = __builtin_amdgcn_mfma_f32_16x16x32_bf16(af[i], bfr[j], acc[i][j], 0, 0, 0);
            __builtin_amdgcn_s_setprio(0);
        }
        __syncthreads();
    }

    #pragma unroll
    for (int i = 0; i < 4; i++) {
        #pragma unroll
        for (int j = 0; j < 2; j++) {
            int rbase = m0 + wr*64 + i*16 + gg*4;
            int c = wc*32 + j*16 + li;
            #pragma unroll
            for (int jj = 0; jj < 4; jj++)
                U[((size_t)b*NQ + rbase + jj)*DD + o*64 + c] = (bf16)acc[i][j][jj];
        }
    }
}

// ---------------- per-batch scaled Wo^T ----------------
__global__ __launch_bounds__(256) void scale_wot(const bf16* __restrict__ WoT,
                                                 const float* __restrict__ ssq,
                                                 bf16* __restrict__ out)
{
    int idx = blockIdx.x * 256 + threadIdx.x;
    int c8 = idx & 63;
    int c  = (idx >> 6) & 511;
    int b  = idx >> 15;
    int h  = c8 >> 3;
    float va = ssq[b*8 + h] * (1.0f / ((float)NQ * (float)NKV));
    float s  = rsqrtf(va + 1e-5f);
    bf16x8 v = *(const bf16x8*)(WoT + ((size_t)c << 9) + c8*8);
    bf16x8 r;
    #pragma unroll
    for (int i = 0; i < 8; i++) r[i] = (bf16)((float)v[i] * s);
    *(bf16x8*)(out + ((size_t)idx << 3)) = r;
}

// ======================================================================
extern "C" void kernel_launch(void* const* d_in, const int* in_sizes, int n_in,
                              void* d_out, int out_size, void* d_ws, size_t ws_size,
                              hipStream_t stream)
{
    const void* queries = d_in[0];
    const void* Wq = d_in[1];  const void* bq = d_in[2];
    const void* Wk = d_in[3];  const void* bk = d_in[4];
    const void* Wv = d_in[5];  const void* bv = d_in[6];
    const void* Wo = d_in[7];  const void* bo = d_in[8];
    const void* srw = d_in[9]; const void* srb = d_in[10];
    const void* lng = d_in[11]; const void* lnb = d_in[12];
    const void* tw  = d_in[13];
    // d_in[14] = tb: cancels in softmax; unused.

    char* ws = (char*)d_ws;
    bf16* WqT = (bf16*)(ws + OFF_WQT);
    bf16* WkT = (bf16*)(ws + OFF_WKT);
    bf16* WvT = (bf16*)(ws + OFF_WVT);
    bf16* WoT = (bf16*)(ws + OFF_WOT);
    bf16* xb  = (bf16*)(ws + OFF_X);
    bf16* Kt  = (bf16*)(ws + OFF_KT);
    bf16* VTb = (bf16*)(ws + OFF_VT);
    bf16* Qf  = (bf16*)(ws + OFF_QF);
    bf16* Ub  = (bf16*)(ws + OFF_U);
    float* ss = (float*)(ws + OFF_SS);
    bf16* sm  = (bf16*)(ws + OFF_SM);
    float* twf = (float*)(ws + OFF_TWF);
    int* flag = (int*)(ws + OFF_FLG);
    bf16* WoTp = (bf16*)(ws + OFF_WOTP);
    bf16* Sb  = (bf16*)(ws + OFF_S);       // S/Dev chunk buffer (in-place mix)
    bf16* Qc  = Ub;                        // converted queries (f32 path)

    // chunk size: prefer CB=8 (75.5 MB chunk stays L3-resident across the
    // gemm_s -> mix -> gemm_pv triple); fall back if workspace is smaller.
    int CB = 1;
    if      (OFF_S + 8*8*SPLANE <= ws_size) CB = 8;
    else if (OFF_S + 4*8*SPLANE <= ws_size) CB = 4;
    else if (OFF_S + 2*8*SPLANE <= ws_size) CB = 2;

    detect_dtype<<<dim3(1), dim3(64), 0, stream>>>((const uint32_t*)queries, flag);
    hipMemsetAsync(ss, 0, 128 * sizeof(float), stream);

    convert_q<<<dim3(9216), dim3(256), 0, stream>>>(queries, Qc, flag);
    convert_small<<<dim3(9), dim3(256), 0, stream>>>(bq, bk, bv, bo, srw, srb, lng, lnb, tw, sm, twf, flag);
    transpose512<<<dim3(16, 16, 4), dim3(32, 8), 0, stream>>>(Wq, Wk, Wv, Wo, WqT, WkT, WvT, WoT, flag);

    sr_ln<<<dim3(NB * NKV), dim3(256), 0, stream>>>(queries, Qc, sm, xb, flag);
    gemm_bt<0><<<dim3(32, 4), dim3(256), 0, stream>>>(xb, WkT, sm + SM_BK, Kt, nullptr, nullptr);
    gemm_bt<1><<<dim3(32, 4), dim3(256), 0, stream>>>(xb, WvT, sm + SM_BV, VTb, nullptr, nullptr);
    gemm_bt<4><<<dim3(288, 4), dim3(256), 0, stream>>>((const bf16*)queries, WqT, sm + SM_BQ, Qf, flag, Qc);

    for (int b0 = 0; b0 < NB; b0 += CB) {
        gemm_s<<<dim3(18, 2, CB*8), dim3(256), 0, stream>>>(Qf, Kt, Sb, b0);
        mix_softmax<<<dim3(72, CB), dim3(256), 0, stream>>>(Sb, twf, ss, b0);
        gemm_pv<<<dim3(18, CB*8), dim3(256), 0, stream>>>(Sb, VTb, Ub, b0);
    }

    scale_wot<<<dim3(2048), dim3(256), 0, stream>>>(WoT, ss, WoTp);
    gemm_bt<2><<<dim3(288, 4), dim3(256), 0, stream>>>(Ub, WoTp, sm + SM_BO, (bf16*)d_out, flag, nullptr);
}

// Round 12
// 364.446 us; speedup vs baseline: 1.1396x; 1.0020x over previous
//
#include <hip/hip_runtime.h>
#include <hip/hip_bf16.h>
#include <stdint.h>

// ======================================================================
// EMSA fused pipeline. Device dtype (bf16 vs f32) detected at runtime.
// Algebra:
//  * S_i = Q_i K_i^T /8 once per input head (9.7 GF); head-mix tw applied
//    in a streaming VALU kernel; PV is a clean batched GEMM.
//  * softmax row-sums are 1  =>  instance-norm mean = 1/256 exactly
//  * Dev = P - 1/256; var = mean(Dev^2); out = (Dev@V)*rsqrt(va+eps)
//  * tb cancels in softmax; 1/sqrt(dk) folded into WqT/bq;
//    instance-norm scale folded into per-batch pre-scaled Wo^T.
// R11: mix_softmax reverted to R7's register-lean form (VGPR 48, 70.8us
//     measured) — R10's single-pass v2 hit VGPR 156 / 9.8% occupancy /
//     135us. Clamp dropped (scores bounded). CB=16 -> 8 so the S/Dev
//     chunk (75.5 MB) stays L3-resident across the attn triple.
// ======================================================================

typedef __bf16 bf16;
typedef __bf16 bf16x4 __attribute__((ext_vector_type(4)));
typedef __bf16 bf16x8 __attribute__((ext_vector_type(8)));
typedef float  f32x4  __attribute__((ext_vector_type(4)));

#define LDS_AS  __attribute__((address_space(3)))
#define GLOB_AS __attribute__((address_space(1)))

__device__ __forceinline__ void gload_lds16(const bf16* g, void* l) {
    __builtin_amdgcn_global_load_lds((const GLOB_AS void*)g, (LDS_AS void*)l, 16, 0, 0);
}

// ---------------- constants ----------------
#define NB   16
#define NQ   2304
#define DD   512
#define NKV  256

// workspace layout (bytes)
constexpr size_t OFF_WQT = 0;
constexpr size_t OFF_WKT = 512*512*2;
constexpr size_t OFF_WVT = 2*512*512*2;
constexpr size_t OFF_WOT = 3*512*512*2;
constexpr size_t OFF_X   = 4*512*512*2;
constexpr size_t OFF_KT  = OFF_X  + 4194304;
constexpr size_t OFF_VT  = OFF_KT + 4194304;
constexpr size_t OFF_SS  = OFF_VT + 4194304;
constexpr size_t OFF_SM  = OFF_SS + 512;
constexpr size_t OFF_TWF = OFF_SM + 24064;
constexpr size_t OFF_FLG = OFF_TWF + 256;
constexpr size_t OFF_QF  = OFF_FLG + 256;
constexpr size_t OFF_U   = OFF_QF + (size_t)NB*NQ*DD*2;
constexpr size_t OFF_S   = OFF_U  + (size_t)NB*NQ*DD*2;   // S/Dev chunk buffer
constexpr size_t SPLANE  = (size_t)NQ*NKV*2;
constexpr size_t OFF_WOTP = OFF_X;   // aliases X+KT (dead by scale_wot)

// small-region element offsets
#define SM_BQ  0
#define SM_BK  512
#define SM_BV  1024
#define SM_BO  1536
#define SM_SRW 2048
#define SM_SRB 10240
#define SM_LNG 10752
#define SM_LNB 11264
#define SM_TW  11776

// ---------------- dtype detection ----------------
__global__ __launch_bounds__(64) void detect_dtype(const uint32_t* __restrict__ q,
                                                   int* __restrict__ flag)
{
    int t = threadIdx.x;
    int cnt = 0;
    #pragma unroll
    for (int i = 0; i < 8; i++) {
        uint32_t w = q[t*8 + i];
        int e = (w >> 7) & 0xFF;
        cnt += (e >= 100 && e <= 150) ? 1 : 0;
    }
    #pragma unroll
    for (int m = 1; m < 64; m <<= 1) cnt += __shfl_xor(cnt, m);
    if (t == 0) *flag = (cnt >= 384) ? 0 : 1;   // 0=bf16, 1=f32
}

// ---------------- input conversion (work only for f32 input) ----------------
__global__ __launch_bounds__(256) void convert_q(const void* __restrict__ in,
                                                 bf16* __restrict__ out,
                                                 const int* __restrict__ flag)
{
    if (*flag == 0) return;
    int idx = blockIdx.x * 256 + threadIdx.x;
    f32x4 a = ((const f32x4*)in)[(size_t)idx*2];
    f32x4 b = ((const f32x4*)in)[(size_t)idx*2 + 1];
    bf16x8 r;
    #pragma unroll
    for (int i = 0; i < 4; i++) { r[i] = (bf16)a[i]; r[i+4] = (bf16)b[i]; }
    ((bf16x8*)out)[idx] = r;
}

__global__ __launch_bounds__(256) void convert_small(
    const void* s0, const void* s1, const void* s2, const void* s3,
    const void* s4, const void* s5, const void* s6, const void* s7,
    const void* s8, bf16* __restrict__ dst, float* __restrict__ twf,
    const int* __restrict__ flag)
{
    const void* srcs[9] = {s0,s1,s2,s3,s4,s5,s6,s7,s8};
    const int sizes[9]  = {512,512,512,512,8192,512,512,512,64};
    const int offs[9]   = {SM_BQ,SM_BK,SM_BV,SM_BO,SM_SRW,SM_SRB,SM_LNG,SM_LNB,SM_TW};
    const float scl[9]  = {0.125f,1.f,1.f,1.f,1.f,1.f,1.f,1.f,1.f};
    int b = blockIdx.x;
    const void* s = srcs[b];
    int n = sizes[b], o = offs[b];
    float sc = scl[b];
    bool f32 = (*flag != 0);
    for (int i = threadIdx.x; i < n; i += 256) {
        float v = f32 ? ((const float*)s)[i] : (float)((const bf16*)s)[i];
        dst[o + i] = (bf16)(v * sc);
        if (b == 8) twf[i] = v;
    }
}

// ---------------- weight transpose (512x512) ----------------
__global__ __launch_bounds__(256) void transpose512(
    const void* s0, const void* s1, const void* s2, const void* s3,
    bf16* __restrict__ d0, bf16* __restrict__ d1,
    bf16* __restrict__ d2, bf16* __restrict__ d3,
    const int* __restrict__ flag)
{
    __shared__ bf16 tile[32][33];
    bool f32 = (*flag != 0);
    int wsel = blockIdx.z;
    const void* src = wsel == 0 ? s0 : wsel == 1 ? s1 : wsel == 2 ? s2 : s3;
    bf16*       dst = wsel == 0 ? d0 : wsel == 1 ? d1 : wsel == 2 ? d2 : d3;
    float scl = (wsel == 0) ? 0.125f : 1.0f;
    int c0 = blockIdx.x * 32, n0 = blockIdx.y * 32;
    int tx = threadIdx.x, ty = threadIdx.y;
    #pragma unroll
    for (int i = 0; i < 4; i++) {
        size_t idx = (size_t)(c0 + ty + i*8) * 512 + n0 + tx;
        float v = f32 ? ((const float*)src)[idx] : (float)((const bf16*)src)[idx];
        tile[ty + i*8][tx] = (bf16)(v * scl);
    }
    __syncthreads();
    #pragma unroll
    for (int i = 0; i < 4; i++)
        dst[(size_t)(n0 + ty + i*8) * 512 + c0 + tx] = tile[tx][ty + i*8];
}

// ---------------- depthwise 4x4/s3 conv + LayerNorm ----------------
__global__ __launch_bounds__(256) void sr_ln(
    const void* __restrict__ qraw, const bf16* __restrict__ qc,
    const bf16* __restrict__ sm, bf16* __restrict__ x,
    const int* __restrict__ flag)
{
    const bf16* q = (*flag) ? qc : (const bf16*)qraw;
    const bf16* srw  = sm + SM_SRW;
    const bf16* srb  = sm + SM_SRB;
    const bf16* g    = sm + SM_LNG;
    const bf16* beta = sm + SM_LNB;
    int bo = blockIdx.x;
    int b  = bo >> 8, ok = bo & 255;
    int oh = ok >> 4, ow = ok & 15;
    int t  = threadIdx.x;

    float v[2];
    #pragma unroll
    for (int h = 0; h < 2; h++) {
        int ch = t + h*256;
        float acc = 0.f;
        #pragma unroll
        for (int kh = 0; kh < 4; kh++) {
            int ih = oh*3 - 1 + kh;
            if (ih < 0) continue;
            #pragma unroll
            for (int kw = 0; kw < 4; kw++) {
                int iw = ow*3 - 1 + kw;
                if (iw < 0) continue;
                acc += (float)q[((size_t)b*NQ + ih*48 + iw)*DD + ch]
                     * (float)srw[ch*16 + kh*4 + kw];
            }
        }
        v[h] = acc + (float)srb[ch];
    }
    float s = v[0] + v[1], s2 = v[0]*v[0] + v[1]*v[1];
    #pragma unroll
    for (int m = 1; m < 64; m <<= 1) { s += __shfl_xor(s, m); s2 += __shfl_xor(s2, m); }
    __shared__ float ps[4], ps2[4];
    if ((t & 63) == 0) { ps[t >> 6] = s; ps2[t >> 6] = s2; }
    __syncthreads();
    s  = ps[0] + ps[1] + ps[2] + ps[3];
    s2 = ps2[0] + ps2[1] + ps2[2] + ps2[3];
    float mu  = s * (1.f/512.f);
    float var = s2 * (1.f/512.f) - mu*mu;
    float inv = rsqrtf(var + 1e-5f);
    #pragma unroll
    for (int h = 0; h < 2; h++) {
        int ch = t + h*256;
        float y = (v[h] - mu) * inv * (float)g[ch] + (float)beta[ch];
        x[(size_t)bo * DD + ch] = (bf16)y;
    }
}

// ---------------- generic BT-GEMM: C(M,512) = A(M,512) @ Bt(512,512)^T + bias ----------
// MODE 0: bf16 row-major store. MODE 1: V^T scatter store (b,h,dv,kk).
// MODE 2: output GEMM (per-batch pre-scaled WoT, dtype-branch store).
// MODE 4: A chosen by flag (raw vs converted queries).
template <int MODE>
__global__ __launch_bounds__(256) void gemm_bt(
    const bf16* __restrict__ A, const bf16* __restrict__ Bt,
    const bf16* __restrict__ bias, bf16* __restrict__ C,
    const int* __restrict__ of32, const bf16* __restrict__ A2)
{
    constexpr int K = 512;
    __shared__ bf16 Al[128 * 64];
    __shared__ bf16 Bl[128 * 64];
    const int m0 = blockIdx.x * 128, n0 = blockIdx.y * 128;
    const int t = threadIdx.x;
    const int lane = t & 63, w = t >> 6;
    const int wr = w >> 1, wc = w & 1;
    const int gg = lane >> 4, li = lane & 15;
    const int fsw = (li & 7) << 4;
    bool f32o = false;
    if (MODE == 2) f32o = (*of32 != 0);

    const bf16* Ab = A;
    if (MODE == 4) Ab = (*of32) ? A2 : A;
    const bf16* Btb = Bt;
    if (MODE == 2) Btb = Bt + (size_t)(m0 / 2304) * (512 * 512);

    f32x4 acc[4][4] = {};

    for (int k0 = 0; k0 < K; k0 += 64) {
        #pragma unroll
        for (int p = 0; p < 4; p++) {
            int off = p*4096 + t*16;
            int row = off >> 7;
            int col = ((((off >> 4) & 7) ^ (row & 7)) << 3);
            gload_lds16(Ab + (size_t)(m0 + row)*K + k0 + col, (char*)Al + off);
        }
        #pragma unroll
        for (int p = 0; p < 4; p++) {
            int off = p*4096 + t*16;
            int row = off >> 7;
            int col = ((((off >> 4) & 7) ^ (row & 7)) << 3);
            gload_lds16(Btb + (size_t)(n0 + row)*K + k0 + col, (char*)Bl + off);
        }
        __syncthreads();
        #pragma unroll
        for (int kk = 0; kk < 2; kk++) {
            bf16x8 af[4], bfr[4];
            #pragma unroll
            for (int i = 0; i < 4; i++) {
                af[i]  = *(const bf16x8*)((char*)Al + (wr*64 + i*16 + li)*128 + ((kk*64 + gg*16) ^ fsw));
                bfr[i] = *(const bf16x8*)((char*)Bl + (wc*64 + i*16 + li)*128 + ((kk*64 + gg*16) ^ fsw));
            }
            __builtin_amdgcn_s_setprio(1);
            #pragma unroll
            for (int i = 0; i < 4; i++)
                #pragma unroll
                for (int j = 0; j < 4; j++)
                    acc[i][j] = __builtin_amdgcn_mfma_f32_16x16x32_bf16(af[i], bfr[j], acc[i][j], 0, 0, 0);
            __builtin_amdgcn_s_setprio(0);
        }
        __syncthreads();
    }

    #pragma unroll
    for (int i = 0; i < 4; i++) {
        #pragma unroll
        for (int j = 0; j < 4; j++) {
            int rbase = m0 + wr*64 + i*16 + gg*4;
            int c     = n0 + wc*64 + j*16 + li;
            float bv = (float)bias[c];
            #pragma unroll
            for (int jj = 0; jj < 4; jj++) {
                float val = acc[i][j][jj] + bv;
                int r = rbase + jj;
                if (MODE == 1) {
                    int bb = r >> 8, kk2 = r & 255;
                    int hh = c >> 6, dv = c & 63;
                    C[(((size_t)(bb*8 + hh))*64 + dv)*256 + kk2] = (bf16)val;
                } else if (MODE == 2) {
                    if (f32o) ((float*)C)[(size_t)r * 512 + c] = val;
                    else      C[(size_t)r * 512 + c] = (bf16)val;
                } else {
                    C[(size_t)r * 512 + c] = (bf16)val;
                }
            }
        }
    }
}

// ---------------- S-GEMM: S[plane] = Q_i @ K_i^T  (M=2304,N=256,K=64) ----------------
__global__ __launch_bounds__(256) void gemm_s(
    const bf16* __restrict__ Qf, const bf16* __restrict__ Kt, bf16* __restrict__ S,
    int b0)
{
    __shared__ bf16 Al[128 * 64];
    __shared__ bf16 Bl[128 * 64];
    const int m0 = blockIdx.x * 128, n0 = blockIdx.y * 128;
    const int bo = blockIdx.z;
    const int b = b0 + (bo >> 3), ih = bo & 7;
    const int t = threadIdx.x;
    const int lane = t & 63, w = t >> 6;
    const int wr = w >> 1, wc = w & 1;
    const int gg = lane >> 4, li = lane & 15;
    const int fsw = (li & 7) << 4;

    #pragma unroll
    for (int p = 0; p < 4; p++) {
        int off = p*4096 + t*16;
        int row = off >> 7;
        int col = ((((off >> 4) & 7) ^ (row & 7)) << 3);
        gload_lds16(Qf + ((size_t)(b*NQ + m0 + row))*DD + ih*64 + col, (char*)Al + off);
    }
    #pragma unroll
    for (int p = 0; p < 4; p++) {
        int off = p*4096 + t*16;
        int row = off >> 7;
        int col = ((((off >> 4) & 7) ^ (row & 7)) << 3);
        gload_lds16(Kt + ((size_t)(b*NKV + n0 + row))*DD + ih*64 + col, (char*)Bl + off);
    }
    __syncthreads();

    f32x4 acc[4][4] = {};
    #pragma unroll
    for (int kk = 0; kk < 2; kk++) {
        bf16x8 af[4], bfr[4];
        #pragma unroll
        for (int i = 0; i < 4; i++) {
            af[i]  = *(const bf16x8*)((char*)Al + (wr*64 + i*16 + li)*128 + ((kk*64 + gg*16) ^ fsw));
            bfr[i] = *(const bf16x8*)((char*)Bl + (wc*64 + i*16 + li)*128 + ((kk*64 + gg*16) ^ fsw));
        }
        __builtin_amdgcn_s_setprio(1);
        #pragma unroll
        for (int i = 0; i < 4; i++)
            #pragma unroll
            for (int j = 0; j < 4; j++)
                acc[i][j] = __builtin_amdgcn_mfma_f32_16x16x32_bf16(af[i], bfr[j], acc[i][j], 0, 0, 0);
        __builtin_amdgcn_s_setprio(0);
    }

    bf16* Sb = S + (size_t)bo * NQ * NKV;
    #pragma unroll
    for (int i = 0; i < 4; i++) {
        #pragma unroll
        for (int j = 0; j < 4; j++) {
            int rbase = m0 + wr*64 + i*16 + gg*4;
            int c     = n0 + wc*64 + j*16 + li;
            #pragma unroll
            for (int jj = 0; jj < 4; jj++)
                Sb[(size_t)(rbase + jj) * NKV + c] = (bf16)acc[i][j][jj];
        }
    }
}

// ---------------- mix + softmax + dev + ssq (streaming, IN-PLACE on S) ----------------
// R7 register-lean form (VGPR 48, 65% VALUBusy measured); clamp dropped
// (|scores| bounded << 1 for this op's LN-normalized inputs).
// grid (72, CB); 256 thr = 4 waves; wave handles 8 q-rows; lane covers k=lane*4..+4.
__global__ __launch_bounds__(256) void mix_softmax(
    bf16* __restrict__ S, const float* __restrict__ twf,
    float* __restrict__ ssq_g, int b0)
{
    const int t = threadIdx.x;
    const int lane = t & 63, w = t >> 6;
    const int bl = blockIdx.y;
    const int b  = b0 + bl;
    const int q0 = blockIdx.x * 32 + w * 8;
    __shared__ float rpar[4][8];

    float tw[8][8];
    #pragma unroll
    for (int o = 0; o < 8; o++)
        #pragma unroll
        for (int i = 0; i < 8; i++)
            tw[o][i] = twf[o*8 + i];     // uniform address -> scalar load

    float ssqL[8] = {};
    for (int qi = 0; qi < 8; qi++) {
        float s[8][4];
        #pragma unroll
        for (int i = 0; i < 8; i++) {
            bf16x4 v = *(const bf16x4*)(S + (((size_t)(bl*8 + i))*NQ + (q0 + qi))*NKV + lane*4);
            #pragma unroll
            for (int r = 0; r < 4; r++) s[i][r] = (float)v[r];
        }
        float e[8][4], inv[8];
        #pragma unroll
        for (int o = 0; o < 8; o++) {
            float sum = 0.f;
            #pragma unroll
            for (int r = 0; r < 4; r++) {
                float a = 0.f;
                #pragma unroll
                for (int i = 0; i < 8; i++) a += tw[o][i] * s[i][r];
                e[o][r] = __expf(a);
                sum += e[o][r];
            }
            #pragma unroll
            for (int m = 1; m < 64; m <<= 1) sum += __shfl_xor(sum, m);
            inv[o] = 1.0f / sum;
        }
        #pragma unroll
        for (int o = 0; o < 8; o++) {
            bf16x4 dv;
            #pragma unroll
            for (int r = 0; r < 4; r++) {
                float d = e[o][r] * inv[o] - (1.0f/256.0f);
                ssqL[o] += d * d;
                dv[r] = (bf16)d;
            }
            *(bf16x4*)(S + (((size_t)(bl*8 + o))*NQ + (q0 + qi))*NKV + lane*4) = dv;
        }
    }
    #pragma unroll
    for (int o = 0; o < 8; o++) {
        float s = ssqL[o];
        #pragma unroll
        for (int m = 1; m < 64; m <<= 1) s += __shfl_xor(s, m);
        if (lane == 0) rpar[w][o] = s;
    }
    __syncthreads();
    if (t < 8) {
        float tot = rpar[0][t] + rpar[1][t] + rpar[2][t] + rpar[3][t];
        atomicAdd(&ssq_g[b*8 + t], tot);
    }
}

// ---------------- PV-GEMM: U[b,o-cols] = Dev[plane] @ V[b,o]  (M=2304,N=64,K=256) ----
__global__ __launch_bounds__(256) void gemm_pv(
    const bf16* __restrict__ Dev, const bf16* __restrict__ VT, bf16* __restrict__ U,
    int b0)
{
    __shared__ bf16 Al[128 * 64];
    __shared__ bf16 Bl[64 * 64];
    const int m0 = blockIdx.x * 128;
    const int bo = blockIdx.y;
    const int b = b0 + (bo >> 3), o = bo & 7;
    const int t = threadIdx.x;
    const int lane = t & 63, w = t >> 6;
    const int wr = w >> 1, wc = w & 1;
    const int gg = lane >> 4, li = lane & 15;
    const int fsw = (li & 7) << 4;

    const bf16* Ab = Dev + (size_t)bo * NQ * NKV;
    const bf16* Bb = VT + ((size_t)(b*8 + o)) * 64 * NKV;

    f32x4 acc[4][2] = {};

    for (int k0 = 0; k0 < 256; k0 += 64) {
        #pragma unroll
        for (int p = 0; p < 4; p++) {
            int off = p*4096 + t*16;
            int row = off >> 7;
            int col = ((((off >> 4) & 7) ^ (row & 7)) << 3);
            gload_lds16(Ab + (size_t)(m0 + row)*NKV + k0 + col, (char*)Al + off);
        }
        #pragma unroll
        for (int p = 0; p < 2; p++) {
            int off = p*4096 + t*16;
            int row = off >> 7;
            int col = ((((off >> 4) & 7) ^ (row & 7)) << 3);
            gload_lds16(Bb + (size_t)row*NKV + k0 + col, (char*)Bl + off);
        }
        __syncthreads();
        #pragma unroll
        for (int kk = 0; kk < 2; kk++) {
            bf16x8 af[4], bfr[2];
            #pragma unroll
            for (int i = 0; i < 4; i++)
                af[i] = *(const bf16x8*)((char*)Al + (wr*64 + i*16 + li)*128 + ((kk*64 + gg*16) ^ fsw));
            #pragma unroll
            for (int j = 0; j < 2; j++)
                bfr[j] = *(const bf16x8*)((char*)Bl + (wc*32 + j*16 + li)*128 + ((kk*64 + gg*16) ^ fsw));
            __builtin_amdgcn_s_setprio(1);
            #pragma unroll
            for (int i = 0; i < 4; i++)
                #pragma unroll
                for (int j = 0; j < 2; j++)
                    acc[i][j] = __builtin_amdgcn_mfma_f32_16x16x32_bf16(af[i], bfr[j], acc[i][j], 0, 0, 0);
            __builtin_amdgcn_s_setprio(0);
        }
        __syncthreads();
    }

    #pragma unroll
    for (int i = 0; i < 4; i++) {
        #pragma unroll
        for (int j = 0; j < 2; j++) {
            int rbase = m0 + wr*64 + i*16 + gg*4;
            int c = wc*32 + j*16 + li;
            #pragma unroll
            for (int jj = 0; jj < 4; jj++)
                U[((size_t)b*NQ + rbase + jj)*DD + o*64 + c] = (bf16)acc[i][j][jj];
        }
    }
}

// ---------------- per-batch scaled Wo^T ----------------
__global__ __launch_bounds__(256) void scale_wot(const bf16* __restrict__ WoT,
                                                 const float* __restrict__ ssq,
                                                 bf16* __restrict__ out)
{
    int idx = blockIdx.x * 256 + threadIdx.x;
    int c8 = idx & 63;
    int c  = (idx >> 6) & 511;
    int b  = idx >> 15;
    int h  = c8 >> 3;
    float va = ssq[b*8 + h] * (1.0f / ((float)NQ * (float)NKV));
    float s  = rsqrtf(va + 1e-5f);
    bf16x8 v = *(const bf16x8*)(WoT + ((size_t)c << 9) + c8*8);
    bf16x8 r;
    #pragma unroll
    for (int i = 0; i < 8; i++) r[i] = (bf16)((float)v[i] * s);
    *(bf16x8*)(out + ((size_t)idx << 3)) = r;
}

// ======================================================================
extern "C" void kernel_launch(void* const* d_in, const int* in_sizes, int n_in,
                              void* d_out, int out_size, void* d_ws, size_t ws_size,
                              hipStream_t stream)
{
    const void* queries = d_in[0];
    const void* Wq = d_in[1];  const void* bq = d_in[2];
    const void* Wk = d_in[3];  const void* bk = d_in[4];
    const void* Wv = d_in[5];  const void* bv = d_in[6];
    const void* Wo = d_in[7];  const void* bo = d_in[8];
    const void* srw = d_in[9]; const void* srb = d_in[10];
    const void* lng = d_in[11]; const void* lnb = d_in[12];
    const void* tw  = d_in[13];
    // d_in[14] = tb: cancels in softmax; unused.

    char* ws = (char*)d_ws;
    bf16* WqT = (bf16*)(ws + OFF_WQT);
    bf16* WkT = (bf16*)(ws + OFF_WKT);
    bf16* WvT = (bf16*)(ws + OFF_WVT);
    bf16* WoT = (bf16*)(ws + OFF_WOT);
    bf16* xb  = (bf16*)(ws + OFF_X);
    bf16* Kt  = (bf16*)(ws + OFF_KT);
    bf16* VTb = (bf16*)(ws + OFF_VT);
    bf16* Qf  = (bf16*)(ws + OFF_QF);
    bf16* Ub  = (bf16*)(ws + OFF_U);
    float* ss = (float*)(ws + OFF_SS);
    bf16* sm  = (bf16*)(ws + OFF_SM);
    float* twf = (float*)(ws + OFF_TWF);
    int* flag = (int*)(ws + OFF_FLG);
    bf16* WoTp = (bf16*)(ws + OFF_WOTP);
    bf16* Sb  = (bf16*)(ws + OFF_S);       // S/Dev chunk buffer (in-place mix)
    bf16* Qc  = Ub;                        // converted queries (f32 path)

    // chunk size: prefer CB=8 (75.5 MB chunk stays L3-resident across the
    // gemm_s -> mix -> gemm_pv triple); fall back if workspace is smaller.
    int CB = 1;
    if      (OFF_S + 8*8*SPLANE <= ws_size) CB = 8;
    else if (OFF_S + 4*8*SPLANE <= ws_size) CB = 4;
    else if (OFF_S + 2*8*SPLANE <= ws_size) CB = 2;

    detect_dtype<<<dim3(1), dim3(64), 0, stream>>>((const uint32_t*)queries, flag);
    hipMemsetAsync(ss, 0, 128 * sizeof(float), stream);

    convert_q<<<dim3(9216), dim3(256), 0, stream>>>(queries, Qc, flag);
    convert_small<<<dim3(9), dim3(256), 0, stream>>>(bq, bk, bv, bo, srw, srb, lng, lnb, tw, sm, twf, flag);
    transpose512<<<dim3(16, 16, 4), dim3(32, 8), 0, stream>>>(Wq, Wk, Wv, Wo, WqT, WkT, WvT, WoT, flag);

    sr_ln<<<dim3(NB * NKV), dim3(256), 0, stream>>>(queries, Qc, sm, xb, flag);
    gemm_bt<0><<<dim3(32, 4), dim3(256), 0, stream>>>(xb, WkT, sm + SM_BK, Kt, nullptr, nullptr);
    gemm_bt<1><<<dim3(32, 4), dim3(256), 0, stream>>>(xb, WvT, sm + SM_BV, VTb, nullptr, nullptr);
    gemm_bt<4><<<dim3(288, 4), dim3(256), 0, stream>>>((const bf16*)queries, WqT, sm + SM_BQ, Qf, flag, Qc);

    for (int b0 = 0; b0 < NB; b0 += CB) {
        gemm_s<<<dim3(18, 2, CB*8), dim3(256), 0, stream>>>(Qf, Kt, Sb, b0);
        mix_softmax<<<dim3(72, CB), dim3(256), 0, stream>>>(Sb, twf, ss, b0);
        gemm_pv<<<dim3(18, CB*8), dim3(256), 0, stream>>>(Sb, VTb, Ub, b0);
    }

    scale_wot<<<dim3(2048), dim3(256), 0, stream>>>(WoT, ss, WoTp);
    gemm_bt<2><<<dim3(288, 4), dim3(256), 0, stream>>>(Ub, WoTp, sm + SM_BO, (bf16*)d_out, flag, nullptr);
}

// Round 13
// 329.566 us; speedup vs baseline: 1.2602x; 1.1058x over previous
//
#include <hip/hip_runtime.h>
#include <hip/hip_bf16.h>
#include <stdint.h>

// ======================================================================
// EMSA fused pipeline. Device dtype (bf16 vs f32) detected at runtime.
// Algebra:
//  * S_i = Q_i K_i^T /8 once per input head (9.7 GF); head-mix tw applied
//    in a streaming VALU kernel; PV is a clean batched GEMM.
//  * softmax row-sums are 1  =>  instance-norm mean = 1/256 exactly
//  * Dev = P - 1/256; var = mean(Dev^2); out = (Dev@V)*rsqrt(va+eps)
//  * tb cancels in softmax; 1/sqrt(dk) folded into WqT/bq;
//    instance-norm scale folded into per-batch pre-scaled Wo^T.
// R13: sr_ln v2 — wave-per-output, bf16x8 loads (16 taps x 16B instead of
//     64 scalar 2B loads/thread), srwT pre-transposed [tap][ch], pure
//     shuffle LN (no LDS/barrier). R12's sr_ln was latency-bound at
//     50.6us with everything idle (VALU 10%, HBM 7%).
// ======================================================================

typedef __bf16 bf16;
typedef __bf16 bf16x4 __attribute__((ext_vector_type(4)));
typedef __bf16 bf16x8 __attribute__((ext_vector_type(8)));
typedef float  f32x4  __attribute__((ext_vector_type(4)));

#define LDS_AS  __attribute__((address_space(3)))
#define GLOB_AS __attribute__((address_space(1)))

__device__ __forceinline__ void gload_lds16(const bf16* g, void* l) {
    __builtin_amdgcn_global_load_lds((const GLOB_AS void*)g, (LDS_AS void*)l, 16, 0, 0);
}

// ---------------- constants ----------------
#define NB   16
#define NQ   2304
#define DD   512
#define NKV  256

// workspace layout (bytes)
constexpr size_t OFF_WQT = 0;
constexpr size_t OFF_WKT = 512*512*2;
constexpr size_t OFF_WVT = 2*512*512*2;
constexpr size_t OFF_WOT = 3*512*512*2;
constexpr size_t OFF_X   = 4*512*512*2;
constexpr size_t OFF_KT  = OFF_X  + 4194304;
constexpr size_t OFF_VT  = OFF_KT + 4194304;
constexpr size_t OFF_SS  = OFF_VT + 4194304;
constexpr size_t OFF_SM  = OFF_SS + 512;
constexpr size_t OFF_TWF = OFF_SM + 40192;               // SM now incl. srwT (20032 elems)
constexpr size_t OFF_FLG = OFF_TWF + 256;
constexpr size_t OFF_QF  = OFF_FLG + 256;
constexpr size_t OFF_U   = OFF_QF + (size_t)NB*NQ*DD*2;
constexpr size_t OFF_S   = OFF_U  + (size_t)NB*NQ*DD*2;   // S/Dev chunk buffer
constexpr size_t SPLANE  = (size_t)NQ*NKV*2;
constexpr size_t OFF_WOTP = OFF_X;   // aliases X+KT (dead by scale_wot)

// small-region element offsets
#define SM_BQ   0
#define SM_BK   512
#define SM_BV   1024
#define SM_BO   1536
#define SM_SRW  2048
#define SM_SRB  10240
#define SM_LNG  10752
#define SM_LNB  11264
#define SM_TW   11776
#define SM_SRWT 11840   /* [tap][ch] transposed depthwise weights, 16x512 */

// ---------------- dtype detection ----------------
__global__ __launch_bounds__(64) void detect_dtype(const uint32_t* __restrict__ q,
                                                   int* __restrict__ flag)
{
    int t = threadIdx.x;
    int cnt = 0;
    #pragma unroll
    for (int i = 0; i < 8; i++) {
        uint32_t w = q[t*8 + i];
        int e = (w >> 7) & 0xFF;
        cnt += (e >= 100 && e <= 150) ? 1 : 0;
    }
    #pragma unroll
    for (int m = 1; m < 64; m <<= 1) cnt += __shfl_xor(cnt, m);
    if (t == 0) *flag = (cnt >= 384) ? 0 : 1;   // 0=bf16, 1=f32
}

// ---------------- input conversion (work only for f32 input) ----------------
__global__ __launch_bounds__(256) void convert_q(const void* __restrict__ in,
                                                 bf16* __restrict__ out,
                                                 const int* __restrict__ flag)
{
    if (*flag == 0) return;
    int idx = blockIdx.x * 256 + threadIdx.x;
    f32x4 a = ((const f32x4*)in)[(size_t)idx*2];
    f32x4 b = ((const f32x4*)in)[(size_t)idx*2 + 1];
    bf16x8 r;
    #pragma unroll
    for (int i = 0; i < 4; i++) { r[i] = (bf16)a[i]; r[i+4] = (bf16)b[i]; }
    ((bf16x8*)out)[idx] = r;
}

__global__ __launch_bounds__(256) void convert_small(
    const void* s0, const void* s1, const void* s2, const void* s3,
    const void* s4, const void* s5, const void* s6, const void* s7,
    const void* s8, bf16* __restrict__ dst, float* __restrict__ twf,
    const int* __restrict__ flag)
{
    const void* srcs[9] = {s0,s1,s2,s3,s4,s5,s6,s7,s8};
    const int sizes[9]  = {512,512,512,512,8192,512,512,512,64};
    const int offs[9]   = {SM_BQ,SM_BK,SM_BV,SM_BO,SM_SRW,SM_SRB,SM_LNG,SM_LNB,SM_TW};
    const float scl[9]  = {0.125f,1.f,1.f,1.f,1.f,1.f,1.f,1.f,1.f};
    int b = blockIdx.x;
    const void* s = srcs[b];
    int n = sizes[b], o = offs[b];
    float sc = scl[b];
    bool f32 = (*flag != 0);
    for (int i = threadIdx.x; i < n; i += 256) {
        float v = f32 ? ((const float*)s)[i] : (float)((const bf16*)s)[i];
        dst[o + i] = (bf16)(v * sc);
        if (b == 8) twf[i] = v;
        if (b == 4) {
            // transposed copy: srw is [ch][tap] (i = ch*16 + tap)
            int tap = i & 15, ch = i >> 4;
            dst[SM_SRWT + tap*DD + ch] = (bf16)v;
        }
    }
}

// ---------------- weight transpose (512x512) ----------------
__global__ __launch_bounds__(256) void transpose512(
    const void* s0, const void* s1, const void* s2, const void* s3,
    bf16* __restrict__ d0, bf16* __restrict__ d1,
    bf16* __restrict__ d2, bf16* __restrict__ d3,
    const int* __restrict__ flag)
{
    __shared__ bf16 tile[32][33];
    bool f32 = (*flag != 0);
    int wsel = blockIdx.z;
    const void* src = wsel == 0 ? s0 : wsel == 1 ? s1 : wsel == 2 ? s2 : s3;
    bf16*       dst = wsel == 0 ? d0 : wsel == 1 ? d1 : wsel == 2 ? d2 : d3;
    float scl = (wsel == 0) ? 0.125f : 1.0f;
    int c0 = blockIdx.x * 32, n0 = blockIdx.y * 32;
    int tx = threadIdx.x, ty = threadIdx.y;
    #pragma unroll
    for (int i = 0; i < 4; i++) {
        size_t idx = (size_t)(c0 + ty + i*8) * 512 + n0 + tx;
        float v = f32 ? ((const float*)src)[idx] : (float)((const bf16*)src)[idx];
        tile[ty + i*8][tx] = (bf16)(v * scl);
    }
    __syncthreads();
    #pragma unroll
    for (int i = 0; i < 4; i++)
        dst[(size_t)(n0 + ty + i*8) * 512 + c0 + tx] = tile[tx][ty + i*8];
}

// ---------------- depthwise 4x4/s3 conv + LayerNorm (v2: wave-per-output) ------------
// grid (1024) x 256 thr: wave = one output (b, ok); lane owns 8 channels.
// bf16x8 loads throughout; LN reduce = pure 64-lane shuffles (no LDS).
__global__ __launch_bounds__(256) void sr_ln(
    const void* __restrict__ qraw, const bf16* __restrict__ qc,
    const bf16* __restrict__ sm, bf16* __restrict__ x,
    const int* __restrict__ flag)
{
    const bf16* q = (*flag) ? qc : (const bf16*)qraw;
    const int t = threadIdx.x;
    const int w = t >> 6, lane = t & 63;
    const int pos = blockIdx.x * 4 + w;        // b*256 + ok
    const int b = pos >> 8, ok = pos & 255;
    const int oh = ok >> 4, ow = ok & 15;
    const int c0 = lane * 8;

    float acc[8] = {};
    #pragma unroll
    for (int kh = 0; kh < 4; kh++) {
        int ih = oh*3 - 1 + kh;
        if (ih < 0) continue;                  // wave-uniform branch
        #pragma unroll
        for (int kw = 0; kw < 4; kw++) {
            int iw = ow*3 - 1 + kw;
            if (iw < 0) continue;              // wave-uniform branch
            bf16x8 qv = *(const bf16x8*)(q + ((size_t)b*NQ + ih*48 + iw)*DD + c0);
            bf16x8 wv = *(const bf16x8*)(sm + SM_SRWT + (kh*4 + kw)*DD + c0);
            #pragma unroll
            for (int r = 0; r < 8; r++) acc[r] += (float)qv[r] * (float)wv[r];
        }
    }
    bf16x8 sb = *(const bf16x8*)(sm + SM_SRB + c0);
    #pragma unroll
    for (int r = 0; r < 8; r++) acc[r] += (float)sb[r];

    float s = 0.f, s2 = 0.f;
    #pragma unroll
    for (int r = 0; r < 8; r++) { s += acc[r]; s2 += acc[r]*acc[r]; }
    #pragma unroll
    for (int m = 1; m < 64; m <<= 1) { s += __shfl_xor(s, m); s2 += __shfl_xor(s2, m); }
    float mu  = s * (1.f/512.f);
    float var = s2 * (1.f/512.f) - mu*mu;
    float inv = rsqrtf(var + 1e-5f);

    bf16x8 gv = *(const bf16x8*)(sm + SM_LNG + c0);
    bf16x8 bv = *(const bf16x8*)(sm + SM_LNB + c0);
    bf16x8 outv;
    #pragma unroll
    for (int r = 0; r < 8; r++)
        outv[r] = (bf16)((acc[r] - mu) * inv * (float)gv[r] + (float)bv[r]);
    *(bf16x8*)(x + (size_t)pos * DD + c0) = outv;
}

// ---------------- generic BT-GEMM: C(M,512) = A(M,512) @ Bt(512,512)^T + bias ----------
// MODE 0: bf16 row-major store. MODE 1: V^T scatter store (b,h,dv,kk).
// MODE 2: output GEMM (per-batch pre-scaled WoT, dtype-branch store).
// MODE 4: A chosen by flag (raw vs converted queries).
template <int MODE>
__global__ __launch_bounds__(256) void gemm_bt(
    const bf16* __restrict__ A, const bf16* __restrict__ Bt,
    const bf16* __restrict__ bias, bf16* __restrict__ C,
    const int* __restrict__ of32, const bf16* __restrict__ A2)
{
    constexpr int K = 512;
    __shared__ bf16 Al[128 * 64];
    __shared__ bf16 Bl[128 * 64];
    const int m0 = blockIdx.x * 128, n0 = blockIdx.y * 128;
    const int t = threadIdx.x;
    const int lane = t & 63, w = t >> 6;
    const int wr = w >> 1, wc = w & 1;
    const int gg = lane >> 4, li = lane & 15;
    const int fsw = (li & 7) << 4;
    bool f32o = false;
    if (MODE == 2) f32o = (*of32 != 0);

    const bf16* Ab = A;
    if (MODE == 4) Ab = (*of32) ? A2 : A;
    const bf16* Btb = Bt;
    if (MODE == 2) Btb = Bt + (size_t)(m0 / 2304) * (512 * 512);

    f32x4 acc[4][4] = {};

    for (int k0 = 0; k0 < K; k0 += 64) {
        #pragma unroll
        for (int p = 0; p < 4; p++) {
            int off = p*4096 + t*16;
            int row = off >> 7;
            int col = ((((off >> 4) & 7) ^ (row & 7)) << 3);
            gload_lds16(Ab + (size_t)(m0 + row)*K + k0 + col, (char*)Al + off);
        }
        #pragma unroll
        for (int p = 0; p < 4; p++) {
            int off = p*4096 + t*16;
            int row = off >> 7;
            int col = ((((off >> 4) & 7) ^ (row & 7)) << 3);
            gload_lds16(Btb + (size_t)(n0 + row)*K + k0 + col, (char*)Bl + off);
        }
        __syncthreads();
        #pragma unroll
        for (int kk = 0; kk < 2; kk++) {
            bf16x8 af[4], bfr[4];
            #pragma unroll
            for (int i = 0; i < 4; i++) {
                af[i]  = *(const bf16x8*)((char*)Al + (wr*64 + i*16 + li)*128 + ((kk*64 + gg*16) ^ fsw));
                bfr[i] = *(const bf16x8*)((char*)Bl + (wc*64 + i*16 + li)*128 + ((kk*64 + gg*16) ^ fsw));
            }
            __builtin_amdgcn_s_setprio(1);
            #pragma unroll
            for (int i = 0; i < 4; i++)
                #pragma unroll
                for (int j = 0; j < 4; j++)
                    acc[i][j] = __builtin_amdgcn_mfma_f32_16x16x32_bf16(af[i], bfr[j], acc[i][j], 0, 0, 0);
            __builtin_amdgcn_s_setprio(0);
        }
        __syncthreads();
    }

    #pragma unroll
    for (int i = 0; i < 4; i++) {
        #pragma unroll
        for (int j = 0; j < 4; j++) {
            int rbase = m0 + wr*64 + i*16 + gg*4;
            int c     = n0 + wc*64 + j*16 + li;
            float bv = (float)bias[c];
            #pragma unroll
            for (int jj = 0; jj < 4; jj++) {
                float val = acc[i][j][jj] + bv;
                int r = rbase + jj;
                if (MODE == 1) {
                    int bb = r >> 8, kk2 = r & 255;
                    int hh = c >> 6, dv = c & 63;
                    C[(((size_t)(bb*8 + hh))*64 + dv)*256 + kk2] = (bf16)val;
                } else if (MODE == 2) {
                    if (f32o) ((float*)C)[(size_t)r * 512 + c] = val;
                    else      C[(size_t)r * 512 + c] = (bf16)val;
                } else {
                    C[(size_t)r * 512 + c] = (bf16)val;
                }
            }
        }
    }
}

// ---------------- S-GEMM: S[plane] = Q_i @ K_i^T  (M=2304,N=256,K=64) ----------------
__global__ __launch_bounds__(256) void gemm_s(
    const bf16* __restrict__ Qf, const bf16* __restrict__ Kt, bf16* __restrict__ S,
    int b0)
{
    __shared__ bf16 Al[128 * 64];
    __shared__ bf16 Bl[128 * 64];
    const int m0 = blockIdx.x * 128, n0 = blockIdx.y * 128;
    const int bo = blockIdx.z;
    const int b = b0 + (bo >> 3), ih = bo & 7;
    const int t = threadIdx.x;
    const int lane = t & 63, w = t >> 6;
    const int wr = w >> 1, wc = w & 1;
    const int gg = lane >> 4, li = lane & 15;
    const int fsw = (li & 7) << 4;

    #pragma unroll
    for (int p = 0; p < 4; p++) {
        int off = p*4096 + t*16;
        int row = off >> 7;
        int col = ((((off >> 4) & 7) ^ (row & 7)) << 3);
        gload_lds16(Qf + ((size_t)(b*NQ + m0 + row))*DD + ih*64 + col, (char*)Al + off);
    }
    #pragma unroll
    for (int p = 0; p < 4; p++) {
        int off = p*4096 + t*16;
        int row = off >> 7;
        int col = ((((off >> 4) & 7) ^ (row & 7)) << 3);
        gload_lds16(Kt + ((size_t)(b*NKV + n0 + row))*DD + ih*64 + col, (char*)Bl + off);
    }
    __syncthreads();

    f32x4 acc[4][4] = {};
    #pragma unroll
    for (int kk = 0; kk < 2; kk++) {
        bf16x8 af[4], bfr[4];
        #pragma unroll
        for (int i = 0; i < 4; i++) {
            af[i]  = *(const bf16x8*)((char*)Al + (wr*64 + i*16 + li)*128 + ((kk*64 + gg*16) ^ fsw));
            bfr[i] = *(const bf16x8*)((char*)Bl + (wc*64 + i*16 + li)*128 + ((kk*64 + gg*16) ^ fsw));
        }
        __builtin_amdgcn_s_setprio(1);
        #pragma unroll
        for (int i = 0; i < 4; i++)
            #pragma unroll
            for (int j = 0; j < 4; j++)
                acc[i][j] = __builtin_amdgcn_mfma_f32_16x16x32_bf16(af[i], bfr[j], acc[i][j], 0, 0, 0);
        __builtin_amdgcn_s_setprio(0);
    }

    bf16* Sb = S + (size_t)bo * NQ * NKV;
    #pragma unroll
    for (int i = 0; i < 4; i++) {
        #pragma unroll
        for (int j = 0; j < 4; j++) {
            int rbase = m0 + wr*64 + i*16 + gg*4;
            int c     = n0 + wc*64 + j*16 + li;
            #pragma unroll
            for (int jj = 0; jj < 4; jj++)
                Sb[(size_t)(rbase + jj) * NKV + c] = (bf16)acc[i][j][jj];
        }
    }
}

// ---------------- mix + softmax + dev + ssq (streaming, IN-PLACE on S) ----------------
// R7 register-lean form (VGPR 48). grid (72, CB); 256 thr = 4 waves.
__global__ __launch_bounds__(256) void mix_softmax(
    bf16* __restrict__ S, const float* __restrict__ twf,
    float* __restrict__ ssq_g, int b0)
{
    const int t = threadIdx.x;
    const int lane = t & 63, w = t >> 6;
    const int bl = blockIdx.y;
    const int b  = b0 + bl;
    const int q0 = blockIdx.x * 32 + w * 8;
    __shared__ float rpar[4][8];

    float tw[8][8];
    #pragma unroll
    for (int o = 0; o < 8; o++)
        #pragma unroll
        for (int i = 0; i < 8; i++)
            tw[o][i] = twf[o*8 + i];     // uniform address -> scalar load

    float ssqL[8] = {};
    for (int qi = 0; qi < 8; qi++) {
        float s[8][4];
        #pragma unroll
        for (int i = 0; i < 8; i++) {
            bf16x4 v = *(const bf16x4*)(S + (((size_t)(bl*8 + i))*NQ + (q0 + qi))*NKV + lane*4);
            #pragma unroll
            for (int r = 0; r < 4; r++) s[i][r] = (float)v[r];
        }
        float e[8][4], inv[8];
        #pragma unroll
        for (int o = 0; o < 8; o++) {
            float sum = 0.f;
            #pragma unroll
            for (int r = 0; r < 4; r++) {
                float a = 0.f;
                #pragma unroll
                for (int i = 0; i < 8; i++) a += tw[o][i] * s[i][r];
                e[o][r] = __expf(a);
                sum += e[o][r];
            }
            #pragma unroll
            for (int m = 1; m < 64; m <<= 1) sum += __shfl_xor(sum, m);
            inv[o] = 1.0f / sum;
        }
        #pragma unroll
        for (int o = 0; o < 8; o++) {
            bf16x4 dv;
            #pragma unroll
            for (int r = 0; r < 4; r++) {
                float d = e[o][r] * inv[o] - (1.0f/256.0f);
                ssqL[o] += d * d;
                dv[r] = (bf16)d;
            }
            *(bf16x4*)(S + (((size_t)(bl*8 + o))*NQ + (q0 + qi))*NKV + lane*4) = dv;
        }
    }
    #pragma unroll
    for (int o = 0; o < 8; o++) {
        float s = ssqL[o];
        #pragma unroll
        for (int m = 1; m < 64; m <<= 1) s += __shfl_xor(s, m);
        if (lane == 0) rpar[w][o] = s;
    }
    __syncthreads();
    if (t < 8) {
        float tot = rpar[0][t] + rpar[1][t] + rpar[2][t] + rpar[3][t];
        atomicAdd(&ssq_g[b*8 + t], tot);
    }
}

// ---------------- PV-GEMM: U[b,o-cols] = Dev[plane] @ V[b,o]  (M=2304,N=64,K=256) ----
__global__ __launch_bounds__(256) void gemm_pv(
    const bf16* __restrict__ Dev, const bf16* __restrict__ VT, bf16* __restrict__ U,
    int b0)
{
    __shared__ bf16 Al[128 * 64];
    __shared__ bf16 Bl[64 * 64];
    const int m0 = blockIdx.x * 128;
    const int bo = blockIdx.y;
    const int b = b0 + (bo >> 3), o = bo & 7;
    const int t = threadIdx.x;
    const int lane = t & 63, w = t >> 6;
    const int wr = w >> 1, wc = w & 1;
    const int gg = lane >> 4, li = lane & 15;
    const int fsw = (li & 7) << 4;

    const bf16* Ab = Dev + (size_t)bo * NQ * NKV;
    const bf16* Bb = VT + ((size_t)(b*8 + o)) * 64 * NKV;

    f32x4 acc[4][2] = {};

    for (int k0 = 0; k0 < 256; k0 += 64) {
        #pragma unroll
        for (int p = 0; p < 4; p++) {
            int off = p*4096 + t*16;
            int row = off >> 7;
            int col = ((((off >> 4) & 7) ^ (row & 7)) << 3);
            gload_lds16(Ab + (size_t)(m0 + row)*NKV + k0 + col, (char*)Al + off);
        }
        #pragma unroll
        for (int p = 0; p < 2; p++) {
            int off = p*4096 + t*16;
            int row = off >> 7;
            int col = ((((off >> 4) & 7) ^ (row & 7)) << 3);
            gload_lds16(Bb + (size_t)row*NKV + k0 + col, (char*)Bl + off);
        }
        __syncthreads();
        #pragma unroll
        for (int kk = 0; kk < 2; kk++) {
            bf16x8 af[4], bfr[2];
            #pragma unroll
            for (int i = 0; i < 4; i++)
                af[i] = *(const bf16x8*)((char*)Al + (wr*64 + i*16 + li)*128 + ((kk*64 + gg*16) ^ fsw));
            #pragma unroll
            for (int j = 0; j < 2; j++)
                bfr[j] = *(const bf16x8*)((char*)Bl + (wc*32 + j*16 + li)*128 + ((kk*64 + gg*16) ^ fsw));
            __builtin_amdgcn_s_setprio(1);
            #pragma unroll
            for (int i = 0; i < 4; i++)
                #pragma unroll
                for (int j = 0; j < 2; j++)
                    acc[i][j] = __builtin_amdgcn_mfma_f32_16x16x32_bf16(af[i], bfr[j], acc[i][j], 0, 0, 0);
            __builtin_amdgcn_s_setprio(0);
        }
        __syncthreads();
    }

    #pragma unroll
    for (int i = 0; i < 4; i++) {
        #pragma unroll
        for (int j = 0; j < 2; j++) {
            int rbase = m0 + wr*64 + i*16 + gg*4;
            int c = wc*32 + j*16 + li;
            #pragma unroll
            for (int jj = 0; jj < 4; jj++)
                U[((size_t)b*NQ + rbase + jj)*DD + o*64 + c] = (bf16)acc[i][j][jj];
        }
    }
}

// ---------------- per-batch scaled Wo^T ----------------
__global__ __launch_bounds__(256) void scale_wot(const bf16* __restrict__ WoT,
                                                 const float* __restrict__ ssq,
                                                 bf16* __restrict__ out)
{
    int idx = blockIdx.x * 256 + threadIdx.x;
    int c8 = idx & 63;
    int c  = (idx >> 6) & 511;
    int b  = idx >> 15;
    int h  = c8 >> 3;
    float va = ssq[b*8 + h] * (1.0f / ((float)NQ * (float)NKV));
    float s  = rsqrtf(va + 1e-5f);
    bf16x8 v = *(const bf16x8*)(WoT + ((size_t)c << 9) + c8*8);
    bf16x8 r;
    #pragma unroll
    for (int i = 0; i < 8; i++) r[i] = (bf16)((float)v[i] * s);
    *(bf16x8*)(out + ((size_t)idx << 3)) = r;
}

// ======================================================================
extern "C" void kernel_launch(void* const* d_in, const int* in_sizes, int n_in,
                              void* d_out, int out_size, void* d_ws, size_t ws_size,
                              hipStream_t stream)
{
    const void* queries = d_in[0];
    const void* Wq = d_in[1];  const void* bq = d_in[2];
    const void* Wk = d_in[3];  const void* bk = d_in[4];
    const void* Wv = d_in[5];  const void* bv = d_in[6];
    const void* Wo = d_in[7];  const void* bo = d_in[8];
    const void* srw = d_in[9]; const void* srb = d_in[10];
    const void* lng = d_in[11]; const void* lnb = d_in[12];
    const void* tw  = d_in[13];
    // d_in[14] = tb: cancels in softmax; unused.

    char* ws = (char*)d_ws;
    bf16* WqT = (bf16*)(ws + OFF_WQT);
    bf16* WkT = (bf16*)(ws + OFF_WKT);
    bf16* WvT = (bf16*)(ws + OFF_WVT);
    bf16* WoT = (bf16*)(ws + OFF_WOT);
    bf16* xb  = (bf16*)(ws + OFF_X);
    bf16* Kt  = (bf16*)(ws + OFF_KT);
    bf16* VTb = (bf16*)(ws + OFF_VT);
    bf16* Qf  = (bf16*)(ws + OFF_QF);
    bf16* Ub  = (bf16*)(ws + OFF_U);
    float* ss = (float*)(ws + OFF_SS);
    bf16* sm  = (bf16*)(ws + OFF_SM);
    float* twf = (float*)(ws + OFF_TWF);
    int* flag = (int*)(ws + OFF_FLG);
    bf16* WoTp = (bf16*)(ws + OFF_WOTP);
    bf16* Sb  = (bf16*)(ws + OFF_S);       // S/Dev chunk buffer (in-place mix)
    bf16* Qc  = Ub;                        // converted queries (f32 path)

    // chunk size: prefer CB=8 (75.5 MB chunk stays L3-resident across the
    // gemm_s -> mix -> gemm_pv triple); fall back if workspace is smaller.
    int CB = 1;
    if      (OFF_S + 8*8*SPLANE <= ws_size) CB = 8;
    else if (OFF_S + 4*8*SPLANE <= ws_size) CB = 4;
    else if (OFF_S + 2*8*SPLANE <= ws_size) CB = 2;

    detect_dtype<<<dim3(1), dim3(64), 0, stream>>>((const uint32_t*)queries, flag);
    hipMemsetAsync(ss, 0, 128 * sizeof(float), stream);

    convert_q<<<dim3(9216), dim3(256), 0, stream>>>(queries, Qc, flag);
    convert_small<<<dim3(9), dim3(256), 0, stream>>>(bq, bk, bv, bo, srw, srb, lng, lnb, tw, sm, twf, flag);
    transpose512<<<dim3(16, 16, 4), dim3(32, 8), 0, stream>>>(Wq, Wk, Wv, Wo, WqT, WkT, WvT, WoT, flag);

    sr_ln<<<dim3(NB * NKV / 4), dim3(256), 0, stream>>>(queries, Qc, sm, xb, flag);
    gemm_bt<0><<<dim3(32, 4), dim3(256), 0, stream>>>(xb, WkT, sm + SM_BK, Kt, nullptr, nullptr);
    gemm_bt<1><<<dim3(32, 4), dim3(256), 0, stream>>>(xb, WvT, sm + SM_BV, VTb, nullptr, nullptr);
    gemm_bt<4><<<dim3(288, 4), dim3(256), 0, stream>>>((const bf16*)queries, WqT, sm + SM_BQ, Qf, flag, Qc);

    for (int b0 = 0; b0 < NB; b0 += CB) {
        gemm_s<<<dim3(18, 2, CB*8), dim3(256), 0, stream>>>(Qf, Kt, Sb, b0);
        mix_softmax<<<dim3(72, CB), dim3(256), 0, stream>>>(Sb, twf, ss, b0);
        gemm_pv<<<dim3(18, CB*8), dim3(256), 0, stream>>>(Sb, VTb, Ub, b0);
    }

    scale_wot<<<dim3(2048), dim3(256), 0, stream>>>(WoT, ss, WoTp);
    gemm_bt<2><<<dim3(288, 4), dim3(256), 0, stream>>>(Ub, WoTp, sm + SM_BO, (bf16*)d_out, flag, nullptr);
}

// Round 14
// 294.620 us; speedup vs baseline: 1.4096x; 1.1186x over previous
//
#include <hip/hip_runtime.h>
#include <hip/hip_bf16.h>
#include <stdint.h>

// ======================================================================
// EMSA fused pipeline. Device dtype (bf16 vs f32) detected at runtime.
// Algebra:
//  * S_i = Q_i K_i^T /8 once per input head (9.7 GF); head-mix tw applied
//    in a streaming VALU kernel; PV is a clean batched GEMM.
//  * softmax row-sums are 1  =>  instance-norm mean = 1/256 exactly
//  * Dev = P - 1/256; var = mean(Dev^2); out = (Dev@V)*rsqrt(va+eps)
//  * tb cancels in softmax; 1/sqrt(dk) folded into WqT/bq;
//    instance-norm scale folded into per-batch pre-scaled Wo^T.
// R14: CB back to 16 (R11's CB=8 split cost 20us: 2x45 vs 70.8 — L3
//     theory refuted, parallelism is what matters) + mix grid 4x finer
//     (wave = 4 q-rows, 2304 blocks -> 36 waves/CU vs 14.7% occupancy).
// ======================================================================

typedef __bf16 bf16;
typedef __bf16 bf16x4 __attribute__((ext_vector_type(4)));
typedef __bf16 bf16x8 __attribute__((ext_vector_type(8)));
typedef float  f32x4  __attribute__((ext_vector_type(4)));

#define LDS_AS  __attribute__((address_space(3)))
#define GLOB_AS __attribute__((address_space(1)))

__device__ __forceinline__ void gload_lds16(const bf16* g, void* l) {
    __builtin_amdgcn_global_load_lds((const GLOB_AS void*)g, (LDS_AS void*)l, 16, 0, 0);
}

// ---------------- constants ----------------
#define NB   16
#define NQ   2304
#define DD   512
#define NKV  256

// workspace layout (bytes)
constexpr size_t OFF_WQT = 0;
constexpr size_t OFF_WKT = 512*512*2;
constexpr size_t OFF_WVT = 2*512*512*2;
constexpr size_t OFF_WOT = 3*512*512*2;
constexpr size_t OFF_X   = 4*512*512*2;
constexpr size_t OFF_KT  = OFF_X  + 4194304;
constexpr size_t OFF_VT  = OFF_KT + 4194304;
constexpr size_t OFF_SS  = OFF_VT + 4194304;
constexpr size_t OFF_SM  = OFF_SS + 512;
constexpr size_t OFF_TWF = OFF_SM + 40192;               // SM incl. srwT
constexpr size_t OFF_FLG = OFF_TWF + 256;
constexpr size_t OFF_QF  = OFF_FLG + 256;
constexpr size_t OFF_U   = OFF_QF + (size_t)NB*NQ*DD*2;
constexpr size_t OFF_S   = OFF_U  + (size_t)NB*NQ*DD*2;   // S/Dev chunk buffer
constexpr size_t SPLANE  = (size_t)NQ*NKV*2;
constexpr size_t OFF_WOTP = OFF_X;   // aliases X+KT (dead by scale_wot)

// small-region element offsets
#define SM_BQ   0
#define SM_BK   512
#define SM_BV   1024
#define SM_BO   1536
#define SM_SRW  2048
#define SM_SRB  10240
#define SM_LNG  10752
#define SM_LNB  11264
#define SM_TW   11776
#define SM_SRWT 11840   /* [tap][ch] transposed depthwise weights, 16x512 */

// ---------------- dtype detection ----------------
__global__ __launch_bounds__(64) void detect_dtype(const uint32_t* __restrict__ q,
                                                   int* __restrict__ flag)
{
    int t = threadIdx.x;
    int cnt = 0;
    #pragma unroll
    for (int i = 0; i < 8; i++) {
        uint32_t w = q[t*8 + i];
        int e = (w >> 7) & 0xFF;
        cnt += (e >= 100 && e <= 150) ? 1 : 0;
    }
    #pragma unroll
    for (int m = 1; m < 64; m <<= 1) cnt += __shfl_xor(cnt, m);
    if (t == 0) *flag = (cnt >= 384) ? 0 : 1;   // 0=bf16, 1=f32
}

// ---------------- input conversion (work only for f32 input) ----------------
__global__ __launch_bounds__(256) void convert_q(const void* __restrict__ in,
                                                 bf16* __restrict__ out,
                                                 const int* __restrict__ flag)
{
    if (*flag == 0) return;
    int idx = blockIdx.x * 256 + threadIdx.x;
    f32x4 a = ((const f32x4*)in)[(size_t)idx*2];
    f32x4 b = ((const f32x4*)in)[(size_t)idx*2 + 1];
    bf16x8 r;
    #pragma unroll
    for (int i = 0; i < 4; i++) { r[i] = (bf16)a[i]; r[i+4] = (bf16)b[i]; }
    ((bf16x8*)out)[idx] = r;
}

__global__ __launch_bounds__(256) void convert_small(
    const void* s0, const void* s1, const void* s2, const void* s3,
    const void* s4, const void* s5, const void* s6, const void* s7,
    const void* s8, bf16* __restrict__ dst, float* __restrict__ twf,
    const int* __restrict__ flag)
{
    const void* srcs[9] = {s0,s1,s2,s3,s4,s5,s6,s7,s8};
    const int sizes[9]  = {512,512,512,512,8192,512,512,512,64};
    const int offs[9]   = {SM_BQ,SM_BK,SM_BV,SM_BO,SM_SRW,SM_SRB,SM_LNG,SM_LNB,SM_TW};
    const float scl[9]  = {0.125f,1.f,1.f,1.f,1.f,1.f,1.f,1.f,1.f};
    int b = blockIdx.x;
    const void* s = srcs[b];
    int n = sizes[b], o = offs[b];
    float sc = scl[b];
    bool f32 = (*flag != 0);
    for (int i = threadIdx.x; i < n; i += 256) {
        float v = f32 ? ((const float*)s)[i] : (float)((const bf16*)s)[i];
        dst[o + i] = (bf16)(v * sc);
        if (b == 8) twf[i] = v;
        if (b == 4) {
            // transposed copy: srw is [ch][tap] (i = ch*16 + tap)
            int tap = i & 15, ch = i >> 4;
            dst[SM_SRWT + tap*DD + ch] = (bf16)v;
        }
    }
}

// ---------------- weight transpose (512x512) ----------------
__global__ __launch_bounds__(256) void transpose512(
    const void* s0, const void* s1, const void* s2, const void* s3,
    bf16* __restrict__ d0, bf16* __restrict__ d1,
    bf16* __restrict__ d2, bf16* __restrict__ d3,
    const int* __restrict__ flag)
{
    __shared__ bf16 tile[32][33];
    bool f32 = (*flag != 0);
    int wsel = blockIdx.z;
    const void* src = wsel == 0 ? s0 : wsel == 1 ? s1 : wsel == 2 ? s2 : s3;
    bf16*       dst = wsel == 0 ? d0 : wsel == 1 ? d1 : wsel == 2 ? d2 : d3;
    float scl = (wsel == 0) ? 0.125f : 1.0f;
    int c0 = blockIdx.x * 32, n0 = blockIdx.y * 32;
    int tx = threadIdx.x, ty = threadIdx.y;
    #pragma unroll
    for (int i = 0; i < 4; i++) {
        size_t idx = (size_t)(c0 + ty + i*8) * 512 + n0 + tx;
        float v = f32 ? ((const float*)src)[idx] : (float)((const bf16*)src)[idx];
        tile[ty + i*8][tx] = (bf16)(v * scl);
    }
    __syncthreads();
    #pragma unroll
    for (int i = 0; i < 4; i++)
        dst[(size_t)(n0 + ty + i*8) * 512 + c0 + tx] = tile[tx][ty + i*8];
}

// ---------------- depthwise 4x4/s3 conv + LayerNorm (wave-per-output) ------------
__global__ __launch_bounds__(256) void sr_ln(
    const void* __restrict__ qraw, const bf16* __restrict__ qc,
    const bf16* __restrict__ sm, bf16* __restrict__ x,
    const int* __restrict__ flag)
{
    const bf16* q = (*flag) ? qc : (const bf16*)qraw;
    const int t = threadIdx.x;
    const int w = t >> 6, lane = t & 63;
    const int pos = blockIdx.x * 4 + w;        // b*256 + ok
    const int b = pos >> 8, ok = pos & 255;
    const int oh = ok >> 4, ow = ok & 15;
    const int c0 = lane * 8;

    float acc[8] = {};
    #pragma unroll
    for (int kh = 0; kh < 4; kh++) {
        int ih = oh*3 - 1 + kh;
        if (ih < 0) continue;
        #pragma unroll
        for (int kw = 0; kw < 4; kw++) {
            int iw = ow*3 - 1 + kw;
            if (iw < 0) continue;
            bf16x8 qv = *(const bf16x8*)(q + ((size_t)b*NQ + ih*48 + iw)*DD + c0);
            bf16x8 wv = *(const bf16x8*)(sm + SM_SRWT + (kh*4 + kw)*DD + c0);
            #pragma unroll
            for (int r = 0; r < 8; r++) acc[r] += (float)qv[r] * (float)wv[r];
        }
    }
    bf16x8 sb = *(const bf16x8*)(sm + SM_SRB + c0);
    #pragma unroll
    for (int r = 0; r < 8; r++) acc[r] += (float)sb[r];

    float s = 0.f, s2 = 0.f;
    #pragma unroll
    for (int r = 0; r < 8; r++) { s += acc[r]; s2 += acc[r]*acc[r]; }
    #pragma unroll
    for (int m = 1; m < 64; m <<= 1) { s += __shfl_xor(s, m); s2 += __shfl_xor(s2, m); }
    float mu  = s * (1.f/512.f);
    float var = s2 * (1.f/512.f) - mu*mu;
    float inv = rsqrtf(var + 1e-5f);

    bf16x8 gv = *(const bf16x8*)(sm + SM_LNG + c0);
    bf16x8 bv = *(const bf16x8*)(sm + SM_LNB + c0);
    bf16x8 outv;
    #pragma unroll
    for (int r = 0; r < 8; r++)
        outv[r] = (bf16)((acc[r] - mu) * inv * (float)gv[r] + (float)bv[r]);
    *(bf16x8*)(x + (size_t)pos * DD + c0) = outv;
}

// ---------------- generic BT-GEMM: C(M,512) = A(M,512) @ Bt(512,512)^T + bias ----------
template <int MODE>
__global__ __launch_bounds__(256) void gemm_bt(
    const bf16* __restrict__ A, const bf16* __restrict__ Bt,
    const bf16* __restrict__ bias, bf16* __restrict__ C,
    const int* __restrict__ of32, const bf16* __restrict__ A2)
{
    constexpr int K = 512;
    __shared__ bf16 Al[128 * 64];
    __shared__ bf16 Bl[128 * 64];
    const int m0 = blockIdx.x * 128, n0 = blockIdx.y * 128;
    const int t = threadIdx.x;
    const int lane = t & 63, w = t >> 6;
    const int wr = w >> 1, wc = w & 1;
    const int gg = lane >> 4, li = lane & 15;
    const int fsw = (li & 7) << 4;
    bool f32o = false;
    if (MODE == 2) f32o = (*of32 != 0);

    const bf16* Ab = A;
    if (MODE == 4) Ab = (*of32) ? A2 : A;
    const bf16* Btb = Bt;
    if (MODE == 2) Btb = Bt + (size_t)(m0 / 2304) * (512 * 512);

    f32x4 acc[4][4] = {};

    for (int k0 = 0; k0 < K; k0 += 64) {
        #pragma unroll
        for (int p = 0; p < 4; p++) {
            int off = p*4096 + t*16;
            int row = off >> 7;
            int col = ((((off >> 4) & 7) ^ (row & 7)) << 3);
            gload_lds16(Ab + (size_t)(m0 + row)*K + k0 + col, (char*)Al + off);
        }
        #pragma unroll
        for (int p = 0; p < 4; p++) {
            int off = p*4096 + t*16;
            int row = off >> 7;
            int col = ((((off >> 4) & 7) ^ (row & 7)) << 3);
            gload_lds16(Btb + (size_t)(n0 + row)*K + k0 + col, (char*)Bl + off);
        }
        __syncthreads();
        #pragma unroll
        for (int kk = 0; kk < 2; kk++) {
            bf16x8 af[4], bfr[4];
            #pragma unroll
            for (int i = 0; i < 4; i++) {
                af[i]  = *(const bf16x8*)((char*)Al + (wr*64 + i*16 + li)*128 + ((kk*64 + gg*16) ^ fsw));
                bfr[i] = *(const bf16x8*)((char*)Bl + (wc*64 + i*16 + li)*128 + ((kk*64 + gg*16) ^ fsw));
            }
            __builtin_amdgcn_s_setprio(1);
            #pragma unroll
            for (int i = 0; i < 4; i++)
                #pragma unroll
                for (int j = 0; j < 4; j++)
                    acc[i][j] = __builtin_amdgcn_mfma_f32_16x16x32_bf16(af[i], bfr[j], acc[i][j], 0, 0, 0);
            __builtin_amdgcn_s_setprio(0);
        }
        __syncthreads();
    }

    #pragma unroll
    for (int i = 0; i < 4; i++) {
        #pragma unroll
        for (int j = 0; j < 4; j++) {
            int rbase = m0 + wr*64 + i*16 + gg*4;
            int c     = n0 + wc*64 + j*16 + li;
            float bv = (float)bias[c];
            #pragma unroll
            for (int jj = 0; jj < 4; jj++) {
                float val = acc[i][j][jj] + bv;
                int r = rbase + jj;
                if (MODE == 1) {
                    int bb = r >> 8, kk2 = r & 255;
                    int hh = c >> 6, dv = c & 63;
                    C[(((size_t)(bb*8 + hh))*64 + dv)*256 + kk2] = (bf16)val;
                } else if (MODE == 2) {
                    if (f32o) ((float*)C)[(size_t)r * 512 + c] = val;
                    else      C[(size_t)r * 512 + c] = (bf16)val;
                } else {
                    C[(size_t)r * 512 + c] = (bf16)val;
                }
            }
        }
    }
}

// ---------------- S-GEMM: S[plane] = Q_i @ K_i^T  (M=2304,N=256,K=64) ----------------
__global__ __launch_bounds__(256) void gemm_s(
    const bf16* __restrict__ Qf, const bf16* __restrict__ Kt, bf16* __restrict__ S,
    int b0)
{
    __shared__ bf16 Al[128 * 64];
    __shared__ bf16 Bl[128 * 64];
    const int m0 = blockIdx.x * 128, n0 = blockIdx.y * 128;
    const int bo = blockIdx.z;
    const int b = b0 + (bo >> 3), ih = bo & 7;
    const int t = threadIdx.x;
    const int lane = t & 63, w = t >> 6;
    const int wr = w >> 1, wc = w & 1;
    const int gg = lane >> 4, li = lane & 15;
    const int fsw = (li & 7) << 4;

    #pragma unroll
    for (int p = 0; p < 4; p++) {
        int off = p*4096 + t*16;
        int row = off >> 7;
        int col = ((((off >> 4) & 7) ^ (row & 7)) << 3);
        gload_lds16(Qf + ((size_t)(b*NQ + m0 + row))*DD + ih*64 + col, (char*)Al + off);
    }
    #pragma unroll
    for (int p = 0; p < 4; p++) {
        int off = p*4096 + t*16;
        int row = off >> 7;
        int col = ((((off >> 4) & 7) ^ (row & 7)) << 3);
        gload_lds16(Kt + ((size_t)(b*NKV + n0 + row))*DD + ih*64 + col, (char*)Bl + off);
    }
    __syncthreads();

    f32x4 acc[4][4] = {};
    #pragma unroll
    for (int kk = 0; kk < 2; kk++) {
        bf16x8 af[4], bfr[4];
        #pragma unroll
        for (int i = 0; i < 4; i++) {
            af[i]  = *(const bf16x8*)((char*)Al + (wr*64 + i*16 + li)*128 + ((kk*64 + gg*16) ^ fsw));
            bfr[i] = *(const bf16x8*)((char*)Bl + (wc*64 + i*16 + li)*128 + ((kk*64 + gg*16) ^ fsw));
        }
        __builtin_amdgcn_s_setprio(1);
        #pragma unroll
        for (int i = 0; i < 4; i++)
            #pragma unroll
            for (int j = 0; j < 4; j++)
                acc[i][j] = __builtin_amdgcn_mfma_f32_16x16x32_bf16(af[i], bfr[j], acc[i][j], 0, 0, 0);
        __builtin_amdgcn_s_setprio(0);
    }

    bf16* Sb = S + (size_t)bo * NQ * NKV;
    #pragma unroll
    for (int i = 0; i < 4; i++) {
        #pragma unroll
        for (int j = 0; j < 4; j++) {
            int rbase = m0 + wr*64 + i*16 + gg*4;
            int c     = n0 + wc*64 + j*16 + li;
            #pragma unroll
            for (int jj = 0; jj < 4; jj++)
                Sb[(size_t)(rbase + jj) * NKV + c] = (bf16)acc[i][j][jj];
        }
    }
}

// ---------------- mix + softmax + dev + ssq (streaming, IN-PLACE on S) ----------------
// R7 register-lean inner structure; grid (144, CB): wave = 4 q-rows ->
// 2304 blocks at CB=16 -> ~36 waves/CU (vs R13's 576 blocks / 14.7% occ).
__global__ __launch_bounds__(256) void mix_softmax(
    bf16* __restrict__ S, const float* __restrict__ twf,
    float* __restrict__ ssq_g, int b0)
{
    const int t = threadIdx.x;
    const int lane = t & 63, w = t >> 6;
    const int bl = blockIdx.y;
    const int b  = b0 + bl;
    const int q0 = blockIdx.x * 16 + w * 4;
    __shared__ float rpar[4][8];

    float tw[8][8];
    #pragma unroll
    for (int o = 0; o < 8; o++)
        #pragma unroll
        for (int i = 0; i < 8; i++)
            tw[o][i] = twf[o*8 + i];     // uniform address -> scalar load

    float ssqL[8] = {};
    for (int qi = 0; qi < 4; qi++) {
        float s[8][4];
        #pragma unroll
        for (int i = 0; i < 8; i++) {
            bf16x4 v = *(const bf16x4*)(S + (((size_t)(bl*8 + i))*NQ + (q0 + qi))*NKV + lane*4);
            #pragma unroll
            for (int r = 0; r < 4; r++) s[i][r] = (float)v[r];
        }
        float e[8][4], inv[8];
        #pragma unroll
        for (int o = 0; o < 8; o++) {
            float sum = 0.f;
            #pragma unroll
            for (int r = 0; r < 4; r++) {
                float a = 0.f;
                #pragma unroll
                for (int i = 0; i < 8; i++) a += tw[o][i] * s[i][r];
                e[o][r] = __expf(a);
                sum += e[o][r];
            }
            #pragma unroll
            for (int m = 1; m < 64; m <<= 1) sum += __shfl_xor(sum, m);
            inv[o] = 1.0f / sum;
        }
        #pragma unroll
        for (int o = 0; o < 8; o++) {
            bf16x4 dv;
            #pragma unroll
            for (int r = 0; r < 4; r++) {
                float d = e[o][r] * inv[o] - (1.0f/256.0f);
                ssqL[o] += d * d;
                dv[r] = (bf16)d;
            }
            *(bf16x4*)(S + (((size_t)(bl*8 + o))*NQ + (q0 + qi))*NKV + lane*4) = dv;
        }
    }
    #pragma unroll
    for (int o = 0; o < 8; o++) {
        float s = ssqL[o];
        #pragma unroll
        for (int m = 1; m < 64; m <<= 1) s += __shfl_xor(s, m);
        if (lane == 0) rpar[w][o] = s;
    }
    __syncthreads();
    if (t < 8) {
        float tot = rpar[0][t] + rpar[1][t] + rpar[2][t] + rpar[3][t];
        atomicAdd(&ssq_g[b*8 + t], tot);
    }
}

// ---------------- PV-GEMM: U[b,o-cols] = Dev[plane] @ V[b,o]  (M=2304,N=64,K=256) ----
__global__ __launch_bounds__(256) void gemm_pv(
    const bf16* __restrict__ Dev, const bf16* __restrict__ VT, bf16* __restrict__ U,
    int b0)
{
    __shared__ bf16 Al[128 * 64];
    __shared__ bf16 Bl[64 * 64];
    const int m0 = blockIdx.x * 128;
    const int bo = blockIdx.y;
    const int b = b0 + (bo >> 3), o = bo & 7;
    const int t = threadIdx.x;
    const int lane = t & 63, w = t >> 6;
    const int wr = w >> 1, wc = w & 1;
    const int gg = lane >> 4, li = lane & 15;
    const int fsw = (li & 7) << 4;

    const bf16* Ab = Dev + (size_t)bo * NQ * NKV;
    const bf16* Bb = VT + ((size_t)(b*8 + o)) * 64 * NKV;

    f32x4 acc[4][2] = {};

    for (int k0 = 0; k0 < 256; k0 += 64) {
        #pragma unroll
        for (int p = 0; p < 4; p++) {
            int off = p*4096 + t*16;
            int row = off >> 7;
            int col = ((((off >> 4) & 7) ^ (row & 7)) << 3);
            gload_lds16(Ab + (size_t)(m0 + row)*NKV + k0 + col, (char*)Al + off);
        }
        #pragma unroll
        for (int p = 0; p < 2; p++) {
            int off = p*4096 + t*16;
            int row = off >> 7;
            int col = ((((off >> 4) & 7) ^ (row & 7)) << 3);
            gload_lds16(Bb + (size_t)row*NKV + k0 + col, (char*)Bl + off);
        }
        __syncthreads();
        #pragma unroll
        for (int kk = 0; kk < 2; kk++) {
            bf16x8 af[4], bfr[2];
            #pragma unroll
            for (int i = 0; i < 4; i++)
                af[i] = *(const bf16x8*)((char*)Al + (wr*64 + i*16 + li)*128 + ((kk*64 + gg*16) ^ fsw));
            #pragma unroll
            for (int j = 0; j < 2; j++)
                bfr[j] = *(const bf16x8*)((char*)Bl + (wc*32 + j*16 + li)*128 + ((kk*64 + gg*16) ^ fsw));
            __builtin_amdgcn_s_setprio(1);
            #pragma unroll
            for (int i = 0; i < 4; i++)
                #pragma unroll
                for (int j = 0; j < 2; j++)
                    acc[i][j] = __builtin_amdgcn_mfma_f32_16x16x32_bf16(af[i], bfr[j], acc[i][j], 0, 0, 0);
            __builtin_amdgcn_s_setprio(0);
        }
        __syncthreads();
    }

    #pragma unroll
    for (int i = 0; i < 4; i++) {
        #pragma unroll
        for (int j = 0; j < 2; j++) {
            int rbase = m0 + wr*64 + i*16 + gg*4;
            int c = wc*32 + j*16 + li;
            #pragma unroll
            for (int jj = 0; jj < 4; jj++)
                U[((size_t)b*NQ + rbase + jj)*DD + o*64 + c] = (bf16)acc[i][j][jj];
        }
    }
}

// ---------------- per-batch scaled Wo^T ----------------
__global__ __launch_bounds__(256) void scale_wot(const bf16* __restrict__ WoT,
                                                 const float* __restrict__ ssq,
                                                 bf16* __restrict__ out)
{
    int idx = blockIdx.x * 256 + threadIdx.x;
    int c8 = idx & 63;
    int c  = (idx >> 6) & 511;
    int b  = idx >> 15;
    int h  = c8 >> 3;
    float va = ssq[b*8 + h] * (1.0f / ((float)NQ * (float)NKV));
    float s  = rsqrtf(va + 1e-5f);
    bf16x8 v = *(const bf16x8*)(WoT + ((size_t)c << 9) + c8*8);
    bf16x8 r;
    #pragma unroll
    for (int i = 0; i < 8; i++) r[i] = (bf16)((float)v[i] * s);
    *(bf16x8*)(out + ((size_t)idx << 3)) = r;
}

// ======================================================================
extern "C" void kernel_launch(void* const* d_in, const int* in_sizes, int n_in,
                              void* d_out, int out_size, void* d_ws, size_t ws_size,
                              hipStream_t stream)
{
    const void* queries = d_in[0];
    const void* Wq = d_in[1];  const void* bq = d_in[2];
    const void* Wk = d_in[3];  const void* bk = d_in[4];
    const void* Wv = d_in[5];  const void* bv = d_in[6];
    const void* Wo = d_in[7];  const void* bo = d_in[8];
    const void* srw = d_in[9]; const void* srb = d_in[10];
    const void* lng = d_in[11]; const void* lnb = d_in[12];
    const void* tw  = d_in[13];
    // d_in[14] = tb: cancels in softmax; unused.

    char* ws = (char*)d_ws;
    bf16* WqT = (bf16*)(ws + OFF_WQT);
    bf16* WkT = (bf16*)(ws + OFF_WKT);
    bf16* WvT = (bf16*)(ws + OFF_WVT);
    bf16* WoT = (bf16*)(ws + OFF_WOT);
    bf16* xb  = (bf16*)(ws + OFF_X);
    bf16* Kt  = (bf16*)(ws + OFF_KT);
    bf16* VTb = (bf16*)(ws + OFF_VT);
    bf16* Qf  = (bf16*)(ws + OFF_QF);
    bf16* Ub  = (bf16*)(ws + OFF_U);
    float* ss = (float*)(ws + OFF_SS);
    bf16* sm  = (bf16*)(ws + OFF_SM);
    float* twf = (float*)(ws + OFF_TWF);
    int* flag = (int*)(ws + OFF_FLG);
    bf16* WoTp = (bf16*)(ws + OFF_WOTP);
    bf16* Sb  = (bf16*)(ws + OFF_S);       // S/Dev chunk buffer (in-place mix)
    bf16* Qc  = Ub;                        // converted queries (f32 path)

    // chunk size: largest CB that fits (R7 proved CB=16 fits this harness)
    int CB = 1;
    if      (OFF_S + 16*8*SPLANE <= ws_size) CB = 16;
    else if (OFF_S +  8*8*SPLANE <= ws_size) CB = 8;
    else if (OFF_S +  4*8*SPLANE <= ws_size) CB = 4;
    else if (OFF_S +  2*8*SPLANE <= ws_size) CB = 2;

    detect_dtype<<<dim3(1), dim3(64), 0, stream>>>((const uint32_t*)queries, flag);
    hipMemsetAsync(ss, 0, 128 * sizeof(float), stream);

    convert_q<<<dim3(9216), dim3(256), 0, stream>>>(queries, Qc, flag);
    convert_small<<<dim3(9), dim3(256), 0, stream>>>(bq, bk, bv, bo, srw, srb, lng, lnb, tw, sm, twf, flag);
    transpose512<<<dim3(16, 16, 4), dim3(32, 8), 0, stream>>>(Wq, Wk, Wv, Wo, WqT, WkT, WvT, WoT, flag);

    sr_ln<<<dim3(NB * NKV / 4), dim3(256), 0, stream>>>(queries, Qc, sm, xb, flag);
    gemm_bt<0><<<dim3(32, 4), dim3(256), 0, stream>>>(xb, WkT, sm + SM_BK, Kt, nullptr, nullptr);
    gemm_bt<1><<<dim3(32, 4), dim3(256), 0, stream>>>(xb, WvT, sm + SM_BV, VTb, nullptr, nullptr);
    gemm_bt<4><<<dim3(288, 4), dim3(256), 0, stream>>>((const bf16*)queries, WqT, sm + SM_BQ, Qf, flag, Qc);

    for (int b0 = 0; b0 < NB; b0 += CB) {
        gemm_s<<<dim3(18, 2, CB*8), dim3(256), 0, stream>>>(Qf, Kt, Sb, b0);
        mix_softmax<<<dim3(144, CB), dim3(256), 0, stream>>>(Sb, twf, ss, b0);
        gemm_pv<<<dim3(18, CB*8), dim3(256), 0, stream>>>(Sb, VTb, Ub, b0);
    }

    scale_wot<<<dim3(2048), dim3(256), 0, stream>>>(WoT, ss, WoTp);
    gemm_bt<2><<<dim3(288, 4), dim3(256), 0, stream>>>(Ub, WoTp, sm + SM_BO, (bf16*)d_out, flag, nullptr);
}